// Round 9
// baseline (653.048 us; speedup 1.0000x reference)
//
#include <hip/hip_runtime.h>
#include <cstdint>
#include <cstddef>

// ---------------------------------------------------------------------------
// StationGNN: 3x GraphSAGE(mean) + MLP head.
// R1 fused head; R2 parallel scan; R3 split-bf16 MFMA; R4 hi-only gather;
// R5/R6/R7 counting-sort CSR (CU-exclusive runs + full-grid parallelism).
// R8 findings: top cost is harness ws-poison (fixed); agg & GEMM serialized.
// R9: FUSE agg+GEMM per layer (phase A: mean -> LDS bf16-hi tile; phase B:
//     MFMA GEMM, part0 A straight from LDS). 77.8KB LDS -> 2 blocks/CU so
//     gather of one block overlaps MFMA of the other (m114 co-scheduling).
//     Mean global round-trip + 3 dispatches + mean-lo MFMA eliminated.
//     prep = convert_x+convert_w+hist in one dispatch; parallel bucket scan.
// ---------------------------------------------------------------------------

typedef __attribute__((ext_vector_type(8))) short short8;
typedef __attribute__((ext_vector_type(8))) unsigned short ushort8;
typedef __attribute__((ext_vector_type(4))) float floatx4;

#define BSHIFT 7                 // 128 nodes per bucket
#define MAXB 512

__device__ __forceinline__ float bf2f(unsigned short h) {
    return __uint_as_float(((unsigned int)h) << 16);
}
__device__ __forceinline__ void split2(float x, unsigned short& hi, unsigned short& lo) {
    unsigned int u = __float_as_uint(x);
    hi = (unsigned short)(u >> 16);
    float r = x - __uint_as_float(u & 0xFFFF0000u);
    lo = (unsigned short)(__float_as_uint(r) >> 16);
}

// ------------------- prep: convert_x + convert_w + hist --------------------

__global__ __launch_bounds__(256) void prep_kernel(
    const float* __restrict__ x, unsigned short* __restrict__ xH,
    unsigned short* __restrict__ xL, int total4,
    const float* __restrict__ w0, const float* __restrict__ w1,
    const float* __restrict__ w2, const float* __restrict__ w3,
    const float* __restrict__ w4, const float* __restrict__ w5,
    unsigned short* __restrict__ WH, unsigned short* __restrict__ WL,
    const int* __restrict__ dst, int E, int* __restrict__ bh, int NBUCK,
    int XB, int WB, int HB) {
    __shared__ int lh[MAXB];
    int bid = blockIdx.x;
    int tid = threadIdx.x;
    if (bid < XB) {
        int i = bid * 256 + tid;
        if (i < total4) {
            float4 v = ((const float4*)x)[i];
            unsigned short h0, h1, h2, h3, l0, l1, l2, l3;
            split2(v.x, h0, l0); split2(v.y, h1, l1);
            split2(v.z, h2, l2); split2(v.w, h3, l3);
            ((ushort4*)xH)[i] = make_ushort4(h0, h1, h2, h3);
            ((ushort4*)xL)[i] = make_ushort4(l0, l1, l2, l3);
        }
    } else if (bid < XB + WB) {
        int wb = bid - XB;
        int m = wb >> 4;
        const float* src = (m == 0) ? w0 : (m == 1) ? w1 : (m == 2) ? w2
                           : (m == 3) ? w3 : (m == 4) ? w4 : w5;
        int i = ((wb & 15) << 8) + tid;   // 4096 float4 per matrix
        float4 v = ((const float4*)src)[i];
        unsigned short h0, h1, h2, h3, l0, l1, l2, l3;
        split2(v.x, h0, l0); split2(v.y, h1, l1);
        split2(v.z, h2, l2); split2(v.w, h3, l3);
        ((ushort4*)(WH + (size_t)m * 16384))[i] = make_ushort4(h0, h1, h2, h3);
        ((ushort4*)(WL + (size_t)m * 16384))[i] = make_ushort4(l0, l1, l2, l3);
    } else {
        int hbid = bid - XB - WB;
        for (int i = tid; i < NBUCK; i += 256) lh[i] = 0;
        __syncthreads();
        for (int e = hbid * 256 + tid; e < E; e += HB * 256)
            atomicAdd(&lh[dst[e] >> BSHIFT], 1);
        __syncthreads();
        for (int i = tid; i < NBUCK; i += 256)
            if (lh[i]) atomicAdd(&bh[i], lh[i]);
    }
}

// -------------------- bucket scan (one block, parallel) --------------------

__global__ __launch_bounds__(512) void bucket_scan_kernel(const int* __restrict__ bh,
                                                          int* __restrict__ bucket_base,
                                                          int* __restrict__ bucket_cursor,
                                                          int* __restrict__ row_ptr,
                                                          int NBUCK, int N, int E) {
    __shared__ int s[512];
    int tid = threadIdx.x;
    int v = (tid < NBUCK) ? bh[tid] : 0;
    s[tid] = v;
    __syncthreads();
#pragma unroll
    for (int off = 1; off < 512; off <<= 1) {
        int t = (tid >= off) ? s[tid - off] : 0;
        __syncthreads();
        s[tid] += t;
        __syncthreads();
    }
    int excl = s[tid] - v;
    if (tid < NBUCK) { bucket_base[tid] = excl; bucket_cursor[tid] = excl; }
    if (tid == 0) { bucket_base[NBUCK] = E; row_ptr[N] = E; }
}

// ------------------------------- binsort -----------------------------------

__global__ __launch_bounds__(256) void binsort_kernel(const int* __restrict__ src,
                                                      const int* __restrict__ dst,
                                                      int E, int CHUNK,
                                                      int* __restrict__ bucket_cursor,
                                                      unsigned int* __restrict__ ebuf,
                                                      int NBUCK) {
    __shared__ int lh[MAXB];
    __shared__ int lcur[MAXB];
    __shared__ int gbase[MAXB];
    int e0 = blockIdx.x * CHUNK;
    int e1 = e0 + CHUNK; if (e1 > E) e1 = E;
    for (int i = threadIdx.x; i < NBUCK; i += 256) { lh[i] = 0; lcur[i] = 0; }
    __syncthreads();
    for (int e = e0 + threadIdx.x; e < e1; e += 256)
        atomicAdd(&lh[dst[e] >> BSHIFT], 1);
    __syncthreads();
    for (int b = threadIdx.x; b < NBUCK; b += 256) {
        int c = lh[b];
        gbase[b] = c ? atomicAdd(&bucket_cursor[b], c) : 0;
    }
    __syncthreads();
    for (int e = e0 + threadIdx.x; e < e1; e += 256) {
        int d = dst[e];
        int s = src[e];
        int b = d >> BSHIFT;
        int off = atomicAdd(&lcur[b], 1);
        ebuf[gbase[b] + off] = (unsigned int)s | ((unsigned int)d << 16);
    }
}

// ----------------------------- bucket fill ---------------------------------

__global__ __launch_bounds__(256) void bucket_fill_kernel(const int* __restrict__ bucket_base,
                                                          const unsigned int* __restrict__ ebuf,
                                                          int* __restrict__ row_ptr,
                                                          int* __restrict__ col, int N) {
    __shared__ int cnt[256];
    __shared__ int scan[256];
    __shared__ int cur[256];
    int b = blockIdx.x;
    int nbase = b << BSHIFT;
    int tid = threadIdx.x;
    int gB = bucket_base[b];
    int gEnd = bucket_base[b + 1];
    cnt[tid] = 0;
    __syncthreads();
    for (int e = gB + tid; e < gEnd; e += 256)
        atomicAdd(&cnt[(ebuf[e] >> 16) - nbase], 1);
    __syncthreads();
    int v = cnt[tid];
    scan[tid] = v;
    __syncthreads();
#pragma unroll
    for (int off = 1; off < 256; off <<= 1) {
        int t = (tid >= off) ? scan[tid - off] : 0;
        __syncthreads();
        scan[tid] += t;
        __syncthreads();
    }
    int excl = scan[tid] - v;
    int n = nbase + tid;
    if (tid < 128 && n < N) row_ptr[n] = gB + excl;
    cur[tid] = gB + excl;
    __syncthreads();
    for (int e = gB + tid; e < gEnd; e += 256) {
        unsigned int pv = ebuf[e];
        int s = (int)(pv & 0xFFFFu);
        int d = (int)(pv >> 16);
        int p = atomicAdd(&cur[d - nbase], 1);
        col[p] = s;
    }
}

// ---------------- fused layer: mean-agg (phase A) + MFMA GEMM --------------
// out[n][j] = ReLU( mean[n]@Wl[j] + x[n]@Wr[j] + bias[j] )
// Block = 128 nodes x 128 outs, 4 waves (2x2 quadrants of 64x64).
// Phase A: wave wv computes mean rows [32wv,32wv+32) into Am (bf16 hi, fp32
// accumulated). Phase B part0: A from Am (2 MFMA: ah*wh + ah*wl);
// part1: x hi+lo staged from global (3 MFMA).
__global__ __launch_bounds__(256, 2) void sage_layer_fused(
    const unsigned short* __restrict__ a1H, const unsigned short* __restrict__ a1L,
    const int* __restrict__ row_ptr, const int* __restrict__ col,
    const unsigned short* __restrict__ wlH, const unsigned short* __restrict__ wlL,
    const unsigned short* __restrict__ wrH, const unsigned short* __restrict__ wrL,
    const float* __restrict__ bias,
    unsigned short* __restrict__ outH, unsigned short* __restrict__ outL, int N) {
    __shared__ unsigned short Am[128][144];   // mean hi; stride 144 (16B-aligned rows)
    __shared__ unsigned short Sa[128][40];    // part1 A hi staging
    __shared__ unsigned short Sl[128][40];    // part1 A lo staging
    __shared__ unsigned short Swh[128][40];   // W hi staging
    __shared__ unsigned short Swl[128][40];   // W lo staging
    int tid = threadIdx.x;
    int n0 = blockIdx.x * 128;
    int wv = tid >> 6, lane = tid & 63;
    int wm = wv & 1, wn = wv >> 1;
    int r16 = lane & 15, q = lane >> 4, q8 = q * 8;

    // ---------------- phase A: mean into Am ----------------
    for (int ii = 0; ii < 32; ++ii) {
        int row = (wv << 5) + ii;
        int n = n0 + row;
        float ax = 0.f, ay = 0.f, bx = 0.f, by = 0.f;
        float cx = 0.f, cy = 0.f, dx = 0.f, dy = 0.f;
        float vx = 0.f, vy = 0.f;
        if (n < N) {
            int beg = row_ptr[n];
            int end = row_ptr[n + 1];
            int i = beg;
            for (; i + 3 < end; i += 4) {
                int s0 = col[i], s1 = col[i + 1], s2 = col[i + 2], s3 = col[i + 3];
                ushort2 h0 = ((const ushort2*)(a1H + (size_t)s0 * 128))[lane];
                ushort2 h1 = ((const ushort2*)(a1H + (size_t)s1 * 128))[lane];
                ushort2 h2 = ((const ushort2*)(a1H + (size_t)s2 * 128))[lane];
                ushort2 h3 = ((const ushort2*)(a1H + (size_t)s3 * 128))[lane];
                ax += bf2f(h0.x); ay += bf2f(h0.y);
                bx += bf2f(h1.x); by += bf2f(h1.y);
                cx += bf2f(h2.x); cy += bf2f(h2.y);
                dx += bf2f(h3.x); dy += bf2f(h3.y);
            }
            for (; i < end; ++i) {
                int s0 = col[i];
                ushort2 h0 = ((const ushort2*)(a1H + (size_t)s0 * 128))[lane];
                ax += bf2f(h0.x); ay += bf2f(h0.y);
            }
            int d = end - beg;
            float inv = 1.0f / (float)(d > 0 ? d : 1);
            vx = (ax + bx + cx + dx) * inv;
            vy = (ay + by + cy + dy) * inv;
        }
        unsigned short hx = (unsigned short)(__float_as_uint(vx) >> 16);
        unsigned short hy = (unsigned short)(__float_as_uint(vy) >> 16);
        *(ushort2*)&Am[row][2 * lane] = make_ushort2(hx, hy);
    }

    floatx4 acc[4][4];
#pragma unroll
    for (int mi = 0; mi < 4; ++mi)
#pragma unroll
        for (int ni = 0; ni < 4; ++ni) {
            floatx4 z = {0.f, 0.f, 0.f, 0.f};
            acc[mi][ni] = z;
        }

    int tc = (tid & 3) * 8;
    int tr = tid >> 2;

    // ---------------- part 0: mean @ Wl (A from Am, 2 MFMA) ----------------
    for (int kk = 0; kk < 128; kk += 32) {
        __syncthreads();
#pragma unroll
        for (int rr = 0; rr < 2; ++rr) {
            int row = tr + 64 * rr;
            *(ushort8*)&Swh[row][tc] = *(const ushort8*)&wlH[(size_t)row * 128 + kk + tc];
            *(ushort8*)&Swl[row][tc] = *(const ushort8*)&wlL[(size_t)row * 128 + kk + tc];
        }
        __syncthreads();
        short8 am[4];
#pragma unroll
        for (int mi = 0; mi < 4; ++mi)
            am[mi] = *(const short8*)&Am[64 * wm + 16 * mi + r16][kk + q8];
#pragma unroll
        for (int ni = 0; ni < 4; ++ni) {
            int row = 64 * wn + 16 * ni + r16;
            short8 bh = *(const short8*)&Swh[row][q8];
            short8 bl = *(const short8*)&Swl[row][q8];
#pragma unroll
            for (int mi = 0; mi < 4; ++mi) {
                acc[mi][ni] = __builtin_amdgcn_mfma_f32_16x16x32_bf16(am[mi], bh, acc[mi][ni], 0, 0, 0);
                acc[mi][ni] = __builtin_amdgcn_mfma_f32_16x16x32_bf16(am[mi], bl, acc[mi][ni], 0, 0, 0);
            }
        }
    }

    // ---------------- part 1: x @ Wr (hi+lo staged, 3 MFMA) ----------------
    for (int kk = 0; kk < 128; kk += 32) {
        __syncthreads();
#pragma unroll
        for (int rr = 0; rr < 2; ++rr) {
            int row = tr + 64 * rr;
            int n = n0 + row;
            ushort8 vh = {0, 0, 0, 0, 0, 0, 0, 0};
            ushort8 vl = {0, 0, 0, 0, 0, 0, 0, 0};
            if (n < N) {
                vh = *(const ushort8*)&a1H[(size_t)n * 128 + kk + tc];
                vl = *(const ushort8*)&a1L[(size_t)n * 128 + kk + tc];
            }
            *(ushort8*)&Sa[row][tc] = vh;
            *(ushort8*)&Sl[row][tc] = vl;
            *(ushort8*)&Swh[row][tc] = *(const ushort8*)&wrH[(size_t)row * 128 + kk + tc];
            *(ushort8*)&Swl[row][tc] = *(const ushort8*)&wrL[(size_t)row * 128 + kk + tc];
        }
        __syncthreads();
        short8 ah[4], al[4];
#pragma unroll
        for (int mi = 0; mi < 4; ++mi) {
            int row = 64 * wm + 16 * mi + r16;
            ah[mi] = *(const short8*)&Sa[row][q8];
            al[mi] = *(const short8*)&Sl[row][q8];
        }
#pragma unroll
        for (int ni = 0; ni < 4; ++ni) {
            int row = 64 * wn + 16 * ni + r16;
            short8 bh = *(const short8*)&Swh[row][q8];
            short8 bl = *(const short8*)&Swl[row][q8];
#pragma unroll
            for (int mi = 0; mi < 4; ++mi) {
                acc[mi][ni] = __builtin_amdgcn_mfma_f32_16x16x32_bf16(ah[mi], bh, acc[mi][ni], 0, 0, 0);
                acc[mi][ni] = __builtin_amdgcn_mfma_f32_16x16x32_bf16(al[mi], bh, acc[mi][ni], 0, 0, 0);
                acc[mi][ni] = __builtin_amdgcn_mfma_f32_16x16x32_bf16(ah[mi], bl, acc[mi][ni], 0, 0, 0);
            }
        }
    }

    // ---------------- epilogue: bias + ReLU -> (hi,lo) ----------------
#pragma unroll
    for (int ni = 0; ni < 4; ++ni) {
        int j = 64 * wn + 16 * ni + r16;
        float b = bias[j];
#pragma unroll
        for (int mi = 0; mi < 4; ++mi) {
            floatx4 v = acc[mi][ni];
#pragma unroll
            for (int p = 0; p < 4; ++p) {
                int node = n0 + 64 * wm + 16 * mi + 4 * q + p;
                if (node < N) {
                    float val = fmaxf(v[p] + b, 0.f);
                    unsigned short hi, lo;
                    split2(val, hi, lo);
                    outH[(size_t)node * 128 + j] = hi;
                    outL[(size_t)node * 128 + j] = lo;
                }
            }
        }
    }
}

// ------------------------------ fused head ---------------------------------

__global__ __launch_bounds__(256) void head_fused_kernel(
    const unsigned short* __restrict__ hH, const unsigned short* __restrict__ hL,
    const float* __restrict__ Wh1, const float* __restrict__ bh1,
    const float* __restrict__ Wh2, const float* __restrict__ bh2,
    float* __restrict__ out, int N) {
    __shared__ float As[64][33];
    __shared__ float Bs[32][65];
    __shared__ float Hs[64][65];
    int tid = threadIdx.x;
    int n0 = blockIdx.x * 64;
    int ti = tid & 15;
    int tj = tid >> 4;

    float acc[4][4];
#pragma unroll
    for (int r = 0; r < 4; ++r)
#pragma unroll
        for (int c = 0; c < 4; ++c) acc[r][c] = 0.f;

    for (int kk = 0; kk < 128; kk += 32) {
        int ks = tid & 31, i0 = tid >> 5;
#pragma unroll
        for (int r = 0; r < 8; ++r) {
            int i = i0 + 8 * r;
            int n = n0 + i;
            As[i][ks] = (n < N)
                ? (bf2f(hH[(size_t)n * 128 + kk + ks]) + bf2f(hL[(size_t)n * 128 + kk + ks]))
                : 0.f;
        }
        int jj0 = tid >> 5;
#pragma unroll
        for (int r = 0; r < 8; ++r) {
            int j = jj0 + 8 * r;
            Bs[ks][j] = Wh1[(size_t)j * 128 + kk + ks];
        }
        __syncthreads();
#pragma unroll 4
        for (int k = 0; k < 32; ++k) {
            float4 b = *(const float4*)&Bs[k][4 * tj];
#pragma unroll
            for (int r = 0; r < 4; ++r) {
                float a = As[4 * ti + r][k];
                acc[r][0] += a * b.x; acc[r][1] += a * b.y;
                acc[r][2] += a * b.z; acc[r][3] += a * b.w;
            }
        }
        __syncthreads();
    }
    float4 bv = *(const float4*)&bh1[4 * tj];
#pragma unroll
    for (int r = 0; r < 4; ++r) {
        int i = 4 * ti + r;
        Hs[i][4 * tj + 0] = fmaxf(acc[r][0] + bv.x, 0.f);
        Hs[i][4 * tj + 1] = fmaxf(acc[r][1] + bv.y, 0.f);
        Hs[i][4 * tj + 2] = fmaxf(acc[r][2] + bv.z, 0.f);
        Hs[i][4 * tj + 3] = fmaxf(acc[r][3] + bv.w, 0.f);
    }
    __syncthreads();
    int ni = tid >> 2;
    int c = tid & 3;
    const float* w = Wh2 + (size_t)c * 64;
    float s = bh2[c];
#pragma unroll 8
    for (int k = 0; k < 64; ++k) s += Hs[ni][k] * w[k];
    int n = n0 + ni;
    if (n < N) out[(size_t)n * 4 + c] = s;
}

// ------------------------------- launcher ----------------------------------

extern "C" void kernel_launch(void* const* d_in, const int* in_sizes, int n_in,
                              void* d_out, int out_size, void* d_ws, size_t ws_size,
                              hipStream_t stream) {
    const float* x   = (const float*)d_in[0];
    const int*   ei  = (const int*)d_in[1];
    const float* Wl0 = (const float*)d_in[2];
    const float* bl0 = (const float*)d_in[3];
    const float* Wr0 = (const float*)d_in[4];
    const float* Wl1 = (const float*)d_in[5];
    const float* bl1 = (const float*)d_in[6];
    const float* Wr1 = (const float*)d_in[7];
    const float* Wl2 = (const float*)d_in[8];
    const float* bl2 = (const float*)d_in[9];
    const float* Wr2 = (const float*)d_in[10];
    const float* Wh1 = (const float*)d_in[11];
    const float* bh1 = (const float*)d_in[12];
    const float* Wh2 = (const float*)d_in[13];
    const float* bh2 = (const float*)d_in[14];
    float* out = (float*)d_out;

    const int N = in_sizes[0] / 128;
    const int E = in_sizes[1] / 2;
    const int* src = ei;
    const int* dst = ei + E;
    const int NBUCK = ((N + 127) >> BSHIFT);

    int* row_ptr       = (int*)d_ws;                 // N+1
    int* bh            = row_ptr + N + 1;            // NBUCK
    int* bucket_base   = bh + NBUCK;                 // NBUCK+1
    int* bucket_cursor = bucket_base + NBUCK + 1;    // NBUCK
    unsigned int* ebuf = (unsigned int*)(bucket_cursor + NBUCK);  // E
    int* col           = (int*)(ebuf + E);           // E
    size_t ioff = (((size_t)(N + 1 + 3 * NBUCK + 1 + 2 * (size_t)E)) * sizeof(int) + 255) & ~(size_t)255;
    unsigned short* u0H = (unsigned short*)((char*)d_ws + ioff);  // x pairs / hB pairs
    unsigned short* u0L = u0H + (size_t)N * 128;
    unsigned short* aH  = u0L + (size_t)N * 128;                  // hA pairs
    unsigned short* aL  = aH + (size_t)N * 128;
    unsigned short* WH  = aL + (size_t)N * 128;                   // 6 x 16384
    unsigned short* WL  = WH + 6 * 16384;

    const int gb64 = (N + 63) / 64;
    const int gb128 = (N + 127) / 128;
    const int CHUNK = 2048;
    const int nchunk = (E + CHUNK - 1) / CHUNK;
    const int XB = (N * 32 + 255) / 256;     // convert_x blocks (float4 count = N*32)
    const int WB = 96;                       // convert_w blocks
    const int HB = 256;                      // hist blocks

    // CSR build + conversions
    hipMemsetAsync(bh, 0, (size_t)NBUCK * sizeof(int), stream);
    prep_kernel<<<XB + WB + HB, 256, 0, stream>>>(x, u0H, u0L, N * 32,
                                                  Wl0, Wr0, Wl1, Wr1, Wl2, Wr2,
                                                  WH, WL, dst, E, bh, NBUCK, XB, WB, HB);
    bucket_scan_kernel<<<1, 512, 0, stream>>>(bh, bucket_base, bucket_cursor, row_ptr, NBUCK, N, E);
    binsort_kernel<<<nchunk, 256, 0, stream>>>(src, dst, E, CHUNK, bucket_cursor, ebuf, NBUCK);
    bucket_fill_kernel<<<NBUCK, 256, 0, stream>>>(bucket_base, ebuf, row_ptr, col, N);

    // fused layers (agg + GEMM)
    sage_layer_fused<<<gb128, 256, 0, stream>>>(u0H, u0L, row_ptr, col,
                                                WH + 0 * 16384, WL + 0 * 16384,
                                                WH + 1 * 16384, WL + 1 * 16384,
                                                bl0, aH, aL, N);
    sage_layer_fused<<<gb128, 256, 0, stream>>>(aH, aL, row_ptr, col,
                                                WH + 2 * 16384, WL + 2 * 16384,
                                                WH + 3 * 16384, WL + 3 * 16384,
                                                bl1, u0H, u0L, N);
    sage_layer_fused<<<gb128, 256, 0, stream>>>(u0H, u0L, row_ptr, col,
                                                WH + 4 * 16384, WL + 4 * 16384,
                                                WH + 5 * 16384, WL + 5 * 16384,
                                                bl2, aH, aL, N);

    // fused head MLP
    head_fused_kernel<<<gb64, 256, 0, stream>>>(aH, aL, Wh1, bh1, Wh2, bh2, out, N);
}

// Round 10
// 354.008 us; speedup vs baseline: 1.8447x; 1.8447x over previous
//
#include <hip/hip_runtime.h>
#include <cstdint>
#include <cstddef>

// ---------------------------------------------------------------------------
// StationGNN: 3x GraphSAGE(mean) + MLP head.
// R1 fused head; R2 parallel scan; R3 split-bf16 MFMA; R4 hi-only gather;
// R5-R7 counting-sort CSR; R8 best separated structure (392us).
// R9 fusion FAILED (32x less gather parallelism -> 653us). Reverted.
// R10: R8 structure + hi-only mean (validated by R9 absmax) + half-split
//      ushort4 gather in agg (halved VMEM instr count, 2x bytes in flight).
// ---------------------------------------------------------------------------

typedef __attribute__((ext_vector_type(8))) short short8;
typedef __attribute__((ext_vector_type(8))) unsigned short ushort8;
typedef __attribute__((ext_vector_type(4))) float floatx4;

#define BSHIFT 7                 // 128 nodes per bucket
#define MAXB 512

__device__ __forceinline__ float bf2f(unsigned short h) {
    return __uint_as_float(((unsigned int)h) << 16);
}
__device__ __forceinline__ void split2(float x, unsigned short& hi, unsigned short& lo) {
    unsigned int u = __float_as_uint(x);
    hi = (unsigned short)(u >> 16);
    float r = x - __uint_as_float(u & 0xFFFF0000u);
    lo = (unsigned short)(__float_as_uint(r) >> 16);
}

// ------------------- prep: convert_x + convert_w + hist --------------------

__global__ __launch_bounds__(256) void prep_kernel(
    const float* __restrict__ x, unsigned short* __restrict__ xH,
    unsigned short* __restrict__ xL, int total4,
    const float* __restrict__ w0, const float* __restrict__ w1,
    const float* __restrict__ w2, const float* __restrict__ w3,
    const float* __restrict__ w4, const float* __restrict__ w5,
    unsigned short* __restrict__ WH, unsigned short* __restrict__ WL,
    const int* __restrict__ dst, int E, int* __restrict__ bh, int NBUCK,
    int XB, int WB, int HB) {
    __shared__ int lh[MAXB];
    int bid = blockIdx.x;
    int tid = threadIdx.x;
    if (bid < XB) {
        int i = bid * 256 + tid;
        if (i < total4) {
            float4 v = ((const float4*)x)[i];
            unsigned short h0, h1, h2, h3, l0, l1, l2, l3;
            split2(v.x, h0, l0); split2(v.y, h1, l1);
            split2(v.z, h2, l2); split2(v.w, h3, l3);
            ((ushort4*)xH)[i] = make_ushort4(h0, h1, h2, h3);
            ((ushort4*)xL)[i] = make_ushort4(l0, l1, l2, l3);
        }
    } else if (bid < XB + WB) {
        int wb = bid - XB;
        int m = wb >> 4;
        const float* src = (m == 0) ? w0 : (m == 1) ? w1 : (m == 2) ? w2
                           : (m == 3) ? w3 : (m == 4) ? w4 : w5;
        int i = ((wb & 15) << 8) + tid;   // 4096 float4 per matrix
        float4 v = ((const float4*)src)[i];
        unsigned short h0, h1, h2, h3, l0, l1, l2, l3;
        split2(v.x, h0, l0); split2(v.y, h1, l1);
        split2(v.z, h2, l2); split2(v.w, h3, l3);
        ((ushort4*)(WH + (size_t)m * 16384))[i] = make_ushort4(h0, h1, h2, h3);
        ((ushort4*)(WL + (size_t)m * 16384))[i] = make_ushort4(l0, l1, l2, l3);
    } else {
        int hbid = bid - XB - WB;
        for (int i = tid; i < NBUCK; i += 256) lh[i] = 0;
        __syncthreads();
        for (int e = hbid * 256 + tid; e < E; e += HB * 256)
            atomicAdd(&lh[dst[e] >> BSHIFT], 1);
        __syncthreads();
        for (int i = tid; i < NBUCK; i += 256)
            if (lh[i]) atomicAdd(&bh[i], lh[i]);
    }
}

// -------------------- bucket scan (one block, parallel) --------------------

__global__ __launch_bounds__(512) void bucket_scan_kernel(const int* __restrict__ bh,
                                                          int* __restrict__ bucket_base,
                                                          int* __restrict__ bucket_cursor,
                                                          int* __restrict__ row_ptr,
                                                          int NBUCK, int N, int E) {
    __shared__ int s[512];
    int tid = threadIdx.x;
    int v = (tid < NBUCK) ? bh[tid] : 0;
    s[tid] = v;
    __syncthreads();
#pragma unroll
    for (int off = 1; off < 512; off <<= 1) {
        int t = (tid >= off) ? s[tid - off] : 0;
        __syncthreads();
        s[tid] += t;
        __syncthreads();
    }
    int excl = s[tid] - v;
    if (tid < NBUCK) { bucket_base[tid] = excl; bucket_cursor[tid] = excl; }
    if (tid == 0) { bucket_base[NBUCK] = E; row_ptr[N] = E; }
}

// ------------------------------- binsort -----------------------------------

__global__ __launch_bounds__(256) void binsort_kernel(const int* __restrict__ src,
                                                      const int* __restrict__ dst,
                                                      int E, int CHUNK,
                                                      int* __restrict__ bucket_cursor,
                                                      unsigned int* __restrict__ ebuf,
                                                      int NBUCK) {
    __shared__ int lh[MAXB];
    __shared__ int lcur[MAXB];
    __shared__ int gbase[MAXB];
    int e0 = blockIdx.x * CHUNK;
    int e1 = e0 + CHUNK; if (e1 > E) e1 = E;
    for (int i = threadIdx.x; i < NBUCK; i += 256) { lh[i] = 0; lcur[i] = 0; }
    __syncthreads();
    for (int e = e0 + threadIdx.x; e < e1; e += 256)
        atomicAdd(&lh[dst[e] >> BSHIFT], 1);
    __syncthreads();
    for (int b = threadIdx.x; b < NBUCK; b += 256) {
        int c = lh[b];
        gbase[b] = c ? atomicAdd(&bucket_cursor[b], c) : 0;
    }
    __syncthreads();
    for (int e = e0 + threadIdx.x; e < e1; e += 256) {
        int d = dst[e];
        int s = src[e];
        int b = d >> BSHIFT;
        int off = atomicAdd(&lcur[b], 1);
        ebuf[gbase[b] + off] = (unsigned int)s | ((unsigned int)d << 16);
    }
}

// ----------------------------- bucket fill ---------------------------------

__global__ __launch_bounds__(256) void bucket_fill_kernel(const int* __restrict__ bucket_base,
                                                          const unsigned int* __restrict__ ebuf,
                                                          int* __restrict__ row_ptr,
                                                          int* __restrict__ col, int N) {
    __shared__ int cnt[256];
    __shared__ int scan[256];
    __shared__ int cur[256];
    int b = blockIdx.x;
    int nbase = b << BSHIFT;
    int tid = threadIdx.x;
    int gB = bucket_base[b];
    int gEnd = bucket_base[b + 1];
    cnt[tid] = 0;
    __syncthreads();
    for (int e = gB + tid; e < gEnd; e += 256)
        atomicAdd(&cnt[(ebuf[e] >> 16) - nbase], 1);
    __syncthreads();
    int v = cnt[tid];
    scan[tid] = v;
    __syncthreads();
#pragma unroll
    for (int off = 1; off < 256; off <<= 1) {
        int t = (tid >= off) ? scan[tid - off] : 0;
        __syncthreads();
        scan[tid] += t;
        __syncthreads();
    }
    int excl = scan[tid] - v;
    int n = nbase + tid;
    if (tid < 128 && n < N) row_ptr[n] = gB + excl;
    cur[tid] = gB + excl;
    __syncthreads();
    for (int e = gB + tid; e < gEnd; e += 256) {
        unsigned int pv = ebuf[e];
        int s = (int)(pv & 0xFFFFu);
        int d = (int)(pv >> 16);
        int p = atomicAdd(&cur[d - nbase], 1);
        col[p] = s;
    }
}

// ------------------------------ aggregation --------------------------------
// one wave per node. Lane halves take even/odd neighbors; each lane loads
// ushort4 (8B, 4 features); cross-half combine via shfl_down(32).
// Output: mean hi only (validated: R9 absmax unchanged).
__global__ __launch_bounds__(256) void agg_mean_kernel(
    const unsigned short* __restrict__ inH,
    const int* __restrict__ row_ptr, const int* __restrict__ col,
    unsigned short* __restrict__ mH, int N) {
    int wave = threadIdx.x >> 6;
    int lane = threadIdx.x & 63;
    int n = blockIdx.x * 4 + wave;
    if (n >= N) return;
    int half = lane >> 5;     // even/odd neighbor stream
    int li = lane & 31;       // feature quad index (4 floats)
    int beg = row_ptr[n];
    int end = row_ptr[n + 1];
    float a0 = 0.f, a1 = 0.f, a2 = 0.f, a3 = 0.f;
    float b0 = 0.f, b1 = 0.f, b2 = 0.f, b3 = 0.f;
    int i = beg + half;
    for (; i + 2 < end; i += 4) {
        int s0 = col[i], s1 = col[i + 2];
        ushort4 h0 = ((const ushort4*)(inH + (size_t)s0 * 128))[li];
        ushort4 h1 = ((const ushort4*)(inH + (size_t)s1 * 128))[li];
        a0 += bf2f(h0.x); a1 += bf2f(h0.y); a2 += bf2f(h0.z); a3 += bf2f(h0.w);
        b0 += bf2f(h1.x); b1 += bf2f(h1.y); b2 += bf2f(h1.z); b3 += bf2f(h1.w);
    }
    if (i < end) {
        int s0 = col[i];
        ushort4 h0 = ((const ushort4*)(inH + (size_t)s0 * 128))[li];
        a0 += bf2f(h0.x); a1 += bf2f(h0.y); a2 += bf2f(h0.z); a3 += bf2f(h0.w);
    }
    a0 += b0; a1 += b1; a2 += b2; a3 += b3;
    a0 += __shfl_down(a0, 32);
    a1 += __shfl_down(a1, 32);
    a2 += __shfl_down(a2, 32);
    a3 += __shfl_down(a3, 32);
    if (half == 0) {
        int d = end - beg;
        float inv = 1.0f / (float)(d > 0 ? d : 1);
        ushort4 o;
        o.x = (unsigned short)(__float_as_uint(a0 * inv) >> 16);
        o.y = (unsigned short)(__float_as_uint(a1 * inv) >> 16);
        o.z = (unsigned short)(__float_as_uint(a2 * inv) >> 16);
        o.w = (unsigned short)(__float_as_uint(a3 * inv) >> 16);
        ((ushort4*)(mH + (size_t)n * 128))[li] = o;
    }
}

// ------------------------- split-bf16 MFMA GEMM ----------------------------
// out[n][j] = ReLU( mean[n]@Wl[j] + x[n]@Wr[j] + bias[j] )
// part0: mean hi-only (2 MFMA/k-step); part1: x hi+lo (3 MFMA/k-step).
__global__ __launch_bounds__(256, 2) void sage_gemm_mfma(
    const unsigned short* __restrict__ a0H,
    const unsigned short* __restrict__ a1H, const unsigned short* __restrict__ a1L,
    const unsigned short* __restrict__ wlH, const unsigned short* __restrict__ wlL,
    const unsigned short* __restrict__ wrH, const unsigned short* __restrict__ wrL,
    const float* __restrict__ bias,
    unsigned short* __restrict__ outH, unsigned short* __restrict__ outL, int N) {
    __shared__ unsigned short Ah[128][40];
    __shared__ unsigned short Al[128][40];
    __shared__ unsigned short Wh[128][40];
    __shared__ unsigned short Wl[128][40];
    int tid = threadIdx.x;
    int n0 = blockIdx.x * 128;
    int wv = tid >> 6, lane = tid & 63;
    int wm = wv & 1, wn = wv >> 1;
    int r16 = lane & 15, q = lane >> 4, q8 = q * 8;

    floatx4 acc[4][4];
#pragma unroll
    for (int mi = 0; mi < 4; ++mi)
#pragma unroll
        for (int ni = 0; ni < 4; ++ni) {
            floatx4 z = {0.f, 0.f, 0.f, 0.f};
            acc[mi][ni] = z;
        }

    int tc = (tid & 3) * 8;
    int tr = tid >> 2;

    // ---- part 0: mean(hi) @ Wl ----
    for (int kk = 0; kk < 128; kk += 32) {
        __syncthreads();
#pragma unroll
        for (int rr = 0; rr < 2; ++rr) {
            int row = tr + 64 * rr;
            int n = n0 + row;
            ushort8 vh = {0, 0, 0, 0, 0, 0, 0, 0};
            if (n < N) vh = *(const ushort8*)&a0H[(size_t)n * 128 + kk + tc];
            *(ushort8*)&Ah[row][tc] = vh;
            *(ushort8*)&Wh[row][tc] = *(const ushort8*)&wlH[(size_t)row * 128 + kk + tc];
            *(ushort8*)&Wl[row][tc] = *(const ushort8*)&wlL[(size_t)row * 128 + kk + tc];
        }
        __syncthreads();
        short8 am[4];
#pragma unroll
        for (int mi = 0; mi < 4; ++mi)
            am[mi] = *(const short8*)&Ah[64 * wm + 16 * mi + r16][q8];
#pragma unroll
        for (int ni = 0; ni < 4; ++ni) {
            int row = 64 * wn + 16 * ni + r16;
            short8 bh = *(const short8*)&Wh[row][q8];
            short8 bl = *(const short8*)&Wl[row][q8];
#pragma unroll
            for (int mi = 0; mi < 4; ++mi) {
                acc[mi][ni] = __builtin_amdgcn_mfma_f32_16x16x32_bf16(am[mi], bh, acc[mi][ni], 0, 0, 0);
                acc[mi][ni] = __builtin_amdgcn_mfma_f32_16x16x32_bf16(am[mi], bl, acc[mi][ni], 0, 0, 0);
            }
        }
    }

    // ---- part 1: x(hi+lo) @ Wr ----
    for (int kk = 0; kk < 128; kk += 32) {
        __syncthreads();
#pragma unroll
        for (int rr = 0; rr < 2; ++rr) {
            int row = tr + 64 * rr;
            int n = n0 + row;
            ushort8 vh = {0, 0, 0, 0, 0, 0, 0, 0};
            ushort8 vl = {0, 0, 0, 0, 0, 0, 0, 0};
            if (n < N) {
                vh = *(const ushort8*)&a1H[(size_t)n * 128 + kk + tc];
                vl = *(const ushort8*)&a1L[(size_t)n * 128 + kk + tc];
            }
            *(ushort8*)&Ah[row][tc] = vh;
            *(ushort8*)&Al[row][tc] = vl;
            *(ushort8*)&Wh[row][tc] = *(const ushort8*)&wrH[(size_t)row * 128 + kk + tc];
            *(ushort8*)&Wl[row][tc] = *(const ushort8*)&wrL[(size_t)row * 128 + kk + tc];
        }
        __syncthreads();
        short8 ah[4], al[4];
#pragma unroll
        for (int mi = 0; mi < 4; ++mi) {
            int row = 64 * wm + 16 * mi + r16;
            ah[mi] = *(const short8*)&Ah[row][q8];
            al[mi] = *(const short8*)&Al[row][q8];
        }
#pragma unroll
        for (int ni = 0; ni < 4; ++ni) {
            int row = 64 * wn + 16 * ni + r16;
            short8 bh = *(const short8*)&Wh[row][q8];
            short8 bl = *(const short8*)&Wl[row][q8];
#pragma unroll
            for (int mi = 0; mi < 4; ++mi) {
                acc[mi][ni] = __builtin_amdgcn_mfma_f32_16x16x32_bf16(ah[mi], bh, acc[mi][ni], 0, 0, 0);
                acc[mi][ni] = __builtin_amdgcn_mfma_f32_16x16x32_bf16(al[mi], bh, acc[mi][ni], 0, 0, 0);
                acc[mi][ni] = __builtin_amdgcn_mfma_f32_16x16x32_bf16(ah[mi], bl, acc[mi][ni], 0, 0, 0);
            }
        }
    }

    // ---- epilogue ----
#pragma unroll
    for (int ni = 0; ni < 4; ++ni) {
        int j = 64 * wn + 16 * ni + r16;
        float b = bias[j];
#pragma unroll
        for (int mi = 0; mi < 4; ++mi) {
            floatx4 v = acc[mi][ni];
#pragma unroll
            for (int p = 0; p < 4; ++p) {
                int node = n0 + 64 * wm + 16 * mi + 4 * q + p;
                if (node < N) {
                    float val = fmaxf(v[p] + b, 0.f);
                    unsigned short hi, lo;
                    split2(val, hi, lo);
                    outH[(size_t)node * 128 + j] = hi;
                    outL[(size_t)node * 128 + j] = lo;
                }
            }
        }
    }
}

// ------------------------------ fused head ---------------------------------

__global__ __launch_bounds__(256) void head_fused_kernel(
    const unsigned short* __restrict__ hH, const unsigned short* __restrict__ hL,
    const float* __restrict__ Wh1, const float* __restrict__ bh1,
    const float* __restrict__ Wh2, const float* __restrict__ bh2,
    float* __restrict__ out, int N) {
    __shared__ float As[64][33];
    __shared__ float Bs[32][65];
    __shared__ float Hs[64][65];
    int tid = threadIdx.x;
    int n0 = blockIdx.x * 64;
    int ti = tid & 15;
    int tj = tid >> 4;

    float acc[4][4];
#pragma unroll
    for (int r = 0; r < 4; ++r)
#pragma unroll
        for (int c = 0; c < 4; ++c) acc[r][c] = 0.f;

    for (int kk = 0; kk < 128; kk += 32) {
        int ks = tid & 31, i0 = tid >> 5;
#pragma unroll
        for (int r = 0; r < 8; ++r) {
            int i = i0 + 8 * r;
            int n = n0 + i;
            As[i][ks] = (n < N)
                ? (bf2f(hH[(size_t)n * 128 + kk + ks]) + bf2f(hL[(size_t)n * 128 + kk + ks]))
                : 0.f;
        }
        int jj0 = tid >> 5;
#pragma unroll
        for (int r = 0; r < 8; ++r) {
            int j = jj0 + 8 * r;
            Bs[ks][j] = Wh1[(size_t)j * 128 + kk + ks];
        }
        __syncthreads();
#pragma unroll 4
        for (int k = 0; k < 32; ++k) {
            float4 b = *(const float4*)&Bs[k][4 * tj];
#pragma unroll
            for (int r = 0; r < 4; ++r) {
                float a = As[4 * ti + r][k];
                acc[r][0] += a * b.x; acc[r][1] += a * b.y;
                acc[r][2] += a * b.z; acc[r][3] += a * b.w;
            }
        }
        __syncthreads();
    }
    float4 bv = *(const float4*)&bh1[4 * tj];
#pragma unroll
    for (int r = 0; r < 4; ++r) {
        int i = 4 * ti + r;
        Hs[i][4 * tj + 0] = fmaxf(acc[r][0] + bv.x, 0.f);
        Hs[i][4 * tj + 1] = fmaxf(acc[r][1] + bv.y, 0.f);
        Hs[i][4 * tj + 2] = fmaxf(acc[r][2] + bv.z, 0.f);
        Hs[i][4 * tj + 3] = fmaxf(acc[r][3] + bv.w, 0.f);
    }
    __syncthreads();
    int ni = tid >> 2;
    int c = tid & 3;
    const float* w = Wh2 + (size_t)c * 64;
    float s = bh2[c];
#pragma unroll 8
    for (int k = 0; k < 64; ++k) s += Hs[ni][k] * w[k];
    int n = n0 + ni;
    if (n < N) out[(size_t)n * 4 + c] = s;
}

// ------------------------------- launcher ----------------------------------

extern "C" void kernel_launch(void* const* d_in, const int* in_sizes, int n_in,
                              void* d_out, int out_size, void* d_ws, size_t ws_size,
                              hipStream_t stream) {
    const float* x   = (const float*)d_in[0];
    const int*   ei  = (const int*)d_in[1];
    const float* Wl0 = (const float*)d_in[2];
    const float* bl0 = (const float*)d_in[3];
    const float* Wr0 = (const float*)d_in[4];
    const float* Wl1 = (const float*)d_in[5];
    const float* bl1 = (const float*)d_in[6];
    const float* Wr1 = (const float*)d_in[7];
    const float* Wl2 = (const float*)d_in[8];
    const float* bl2 = (const float*)d_in[9];
    const float* Wr2 = (const float*)d_in[10];
    const float* Wh1 = (const float*)d_in[11];
    const float* bh1 = (const float*)d_in[12];
    const float* Wh2 = (const float*)d_in[13];
    const float* bh2 = (const float*)d_in[14];
    float* out = (float*)d_out;

    const int N = in_sizes[0] / 128;
    const int E = in_sizes[1] / 2;
    const int* src = ei;
    const int* dst = ei + E;
    const int NBUCK = ((N + 127) >> BSHIFT);

    int* row_ptr       = (int*)d_ws;                 // N+1
    int* bh            = row_ptr + N + 1;            // NBUCK
    int* bucket_base   = bh + NBUCK;                 // NBUCK+1
    int* bucket_cursor = bucket_base + NBUCK + 1;    // NBUCK
    unsigned int* ebuf = (unsigned int*)(bucket_cursor + NBUCK);  // E
    int* col           = (int*)(ebuf + E);           // E
    size_t ioff = (((size_t)(N + 1 + 3 * NBUCK + 1 + 2 * (size_t)E)) * sizeof(int) + 255) & ~(size_t)255;
    unsigned short* u0H = (unsigned short*)((char*)d_ws + ioff);  // x / hB pairs
    unsigned short* u0L = u0H + (size_t)N * 128;
    unsigned short* mHb = u0L + (size_t)N * 128;                  // mean hi
    unsigned short* aH  = mHb + (size_t)N * 128;                  // hA pairs
    unsigned short* aL  = aH + (size_t)N * 128;
    unsigned short* WH  = aL + (size_t)N * 128;                   // 6 x 16384
    unsigned short* WL  = WH + 6 * 16384;

    const int nb4 = (N + 3) / 4;
    const int gb64 = (N + 63) / 64;
    const int gb128 = (N + 127) / 128;
    const int CHUNK = 2048;
    const int nchunk = (E + CHUNK - 1) / CHUNK;
    const int XB = (N * 32 + 255) / 256;
    const int WB = 96;
    const int HB = 256;

    // CSR build + conversions
    hipMemsetAsync(bh, 0, (size_t)NBUCK * sizeof(int), stream);
    prep_kernel<<<XB + WB + HB, 256, 0, stream>>>(x, u0H, u0L, N * 32,
                                                  Wl0, Wr0, Wl1, Wr1, Wl2, Wr2,
                                                  WH, WL, dst, E, bh, NBUCK, XB, WB, HB);
    bucket_scan_kernel<<<1, 512, 0, stream>>>(bh, bucket_base, bucket_cursor, row_ptr, NBUCK, N, E);
    binsort_kernel<<<nchunk, 256, 0, stream>>>(src, dst, E, CHUNK, bucket_cursor, ebuf, NBUCK);
    bucket_fill_kernel<<<NBUCK, 256, 0, stream>>>(bucket_base, ebuf, row_ptr, col, N);

    // layer 0
    agg_mean_kernel<<<nb4, 256, 0, stream>>>(u0H, row_ptr, col, mHb, N);
    sage_gemm_mfma<<<gb128, 256, 0, stream>>>(mHb, u0H, u0L,
                                              WH + 0 * 16384, WL + 0 * 16384,
                                              WH + 1 * 16384, WL + 1 * 16384,
                                              bl0, aH, aL, N);
    // layer 1
    agg_mean_kernel<<<nb4, 256, 0, stream>>>(aH, row_ptr, col, mHb, N);
    sage_gemm_mfma<<<gb128, 256, 0, stream>>>(mHb, aH, aL,
                                              WH + 2 * 16384, WL + 2 * 16384,
                                              WH + 3 * 16384, WL + 3 * 16384,
                                              bl1, u0H, u0L, N);
    // layer 2
    agg_mean_kernel<<<nb4, 256, 0, stream>>>(u0H, row_ptr, col, mHb, N);
    sage_gemm_mfma<<<gb128, 256, 0, stream>>>(mHb, u0H, u0L,
                                              WH + 4 * 16384, WL + 4 * 16384,
                                              WH + 5 * 16384, WL + 5 * 16384,
                                              bl2, aH, aL, N);

    // fused head MLP
    head_fused_kernel<<<gb64, 256, 0, stream>>>(aH, aL, Wh1, bh1, Wh2, bh2, out, N);
}

// Round 11
// 334.303 us; speedup vs baseline: 1.9535x; 1.0589x over previous
//
#include <hip/hip_runtime.h>
#include <cstdint>
#include <cstddef>

// ---------------------------------------------------------------------------
// StationGNN: 3x GraphSAGE(mean) + MLP head.
// R1 fused head; R2 parallel scan; R3 split-bf16 MFMA; R4 hi-only gather;
// R5-R7 counting-sort CSR; R8 separated structure; R9 fusion FAILED (revert);
// R10 hi-only mean + half-split gather (354us).
// R11: 4-way-split agg gather: quarter=lane>>4, lane loads ushort8 (16B,
//      8 feats), 4 independent neighbor streams x unroll 2; cross-quarter
//      combine via 2 shfl_downs. Halves VMEM instructions per row again.
// ---------------------------------------------------------------------------

typedef __attribute__((ext_vector_type(8))) short short8;
typedef __attribute__((ext_vector_type(8))) unsigned short ushort8;
typedef __attribute__((ext_vector_type(4))) float floatx4;

#define BSHIFT 7                 // 128 nodes per bucket
#define MAXB 512

__device__ __forceinline__ float bf2f(unsigned short h) {
    return __uint_as_float(((unsigned int)h) << 16);
}
__device__ __forceinline__ void split2(float x, unsigned short& hi, unsigned short& lo) {
    unsigned int u = __float_as_uint(x);
    hi = (unsigned short)(u >> 16);
    float r = x - __uint_as_float(u & 0xFFFF0000u);
    lo = (unsigned short)(__float_as_uint(r) >> 16);
}

// ------------------- prep: convert_x + convert_w + hist --------------------

__global__ __launch_bounds__(256) void prep_kernel(
    const float* __restrict__ x, unsigned short* __restrict__ xH,
    unsigned short* __restrict__ xL, int total4,
    const float* __restrict__ w0, const float* __restrict__ w1,
    const float* __restrict__ w2, const float* __restrict__ w3,
    const float* __restrict__ w4, const float* __restrict__ w5,
    unsigned short* __restrict__ WH, unsigned short* __restrict__ WL,
    const int* __restrict__ dst, int E, int* __restrict__ bh, int NBUCK,
    int XB, int WB, int HB) {
    __shared__ int lh[MAXB];
    int bid = blockIdx.x;
    int tid = threadIdx.x;
    if (bid < XB) {
        int i = bid * 256 + tid;
        if (i < total4) {
            float4 v = ((const float4*)x)[i];
            unsigned short h0, h1, h2, h3, l0, l1, l2, l3;
            split2(v.x, h0, l0); split2(v.y, h1, l1);
            split2(v.z, h2, l2); split2(v.w, h3, l3);
            ((ushort4*)xH)[i] = make_ushort4(h0, h1, h2, h3);
            ((ushort4*)xL)[i] = make_ushort4(l0, l1, l2, l3);
        }
    } else if (bid < XB + WB) {
        int wb = bid - XB;
        int m = wb >> 4;
        const float* src = (m == 0) ? w0 : (m == 1) ? w1 : (m == 2) ? w2
                           : (m == 3) ? w3 : (m == 4) ? w4 : w5;
        int i = ((wb & 15) << 8) + tid;   // 4096 float4 per matrix
        float4 v = ((const float4*)src)[i];
        unsigned short h0, h1, h2, h3, l0, l1, l2, l3;
        split2(v.x, h0, l0); split2(v.y, h1, l1);
        split2(v.z, h2, l2); split2(v.w, h3, l3);
        ((ushort4*)(WH + (size_t)m * 16384))[i] = make_ushort4(h0, h1, h2, h3);
        ((ushort4*)(WL + (size_t)m * 16384))[i] = make_ushort4(l0, l1, l2, l3);
    } else {
        int hbid = bid - XB - WB;
        for (int i = tid; i < NBUCK; i += 256) lh[i] = 0;
        __syncthreads();
        for (int e = hbid * 256 + tid; e < E; e += HB * 256)
            atomicAdd(&lh[dst[e] >> BSHIFT], 1);
        __syncthreads();
        for (int i = tid; i < NBUCK; i += 256)
            if (lh[i]) atomicAdd(&bh[i], lh[i]);
    }
}

// -------------------- bucket scan (one block, parallel) --------------------

__global__ __launch_bounds__(512) void bucket_scan_kernel(const int* __restrict__ bh,
                                                          int* __restrict__ bucket_base,
                                                          int* __restrict__ bucket_cursor,
                                                          int* __restrict__ row_ptr,
                                                          int NBUCK, int N, int E) {
    __shared__ int s[512];
    int tid = threadIdx.x;
    int v = (tid < NBUCK) ? bh[tid] : 0;
    s[tid] = v;
    __syncthreads();
#pragma unroll
    for (int off = 1; off < 512; off <<= 1) {
        int t = (tid >= off) ? s[tid - off] : 0;
        __syncthreads();
        s[tid] += t;
        __syncthreads();
    }
    int excl = s[tid] - v;
    if (tid < NBUCK) { bucket_base[tid] = excl; bucket_cursor[tid] = excl; }
    if (tid == 0) { bucket_base[NBUCK] = E; row_ptr[N] = E; }
}

// ------------------------------- binsort -----------------------------------

__global__ __launch_bounds__(256) void binsort_kernel(const int* __restrict__ src,
                                                      const int* __restrict__ dst,
                                                      int E, int CHUNK,
                                                      int* __restrict__ bucket_cursor,
                                                      unsigned int* __restrict__ ebuf,
                                                      int NBUCK) {
    __shared__ int lh[MAXB];
    __shared__ int lcur[MAXB];
    __shared__ int gbase[MAXB];
    int e0 = blockIdx.x * CHUNK;
    int e1 = e0 + CHUNK; if (e1 > E) e1 = E;
    for (int i = threadIdx.x; i < NBUCK; i += 256) { lh[i] = 0; lcur[i] = 0; }
    __syncthreads();
    for (int e = e0 + threadIdx.x; e < e1; e += 256)
        atomicAdd(&lh[dst[e] >> BSHIFT], 1);
    __syncthreads();
    for (int b = threadIdx.x; b < NBUCK; b += 256) {
        int c = lh[b];
        gbase[b] = c ? atomicAdd(&bucket_cursor[b], c) : 0;
    }
    __syncthreads();
    for (int e = e0 + threadIdx.x; e < e1; e += 256) {
        int d = dst[e];
        int s = src[e];
        int b = d >> BSHIFT;
        int off = atomicAdd(&lcur[b], 1);
        ebuf[gbase[b] + off] = (unsigned int)s | ((unsigned int)d << 16);
    }
}

// ----------------------------- bucket fill ---------------------------------

__global__ __launch_bounds__(256) void bucket_fill_kernel(const int* __restrict__ bucket_base,
                                                          const unsigned int* __restrict__ ebuf,
                                                          int* __restrict__ row_ptr,
                                                          int* __restrict__ col, int N) {
    __shared__ int cnt[256];
    __shared__ int scan[256];
    __shared__ int cur[256];
    int b = blockIdx.x;
    int nbase = b << BSHIFT;
    int tid = threadIdx.x;
    int gB = bucket_base[b];
    int gEnd = bucket_base[b + 1];
    cnt[tid] = 0;
    __syncthreads();
    for (int e = gB + tid; e < gEnd; e += 256)
        atomicAdd(&cnt[(ebuf[e] >> 16) - nbase], 1);
    __syncthreads();
    int v = cnt[tid];
    scan[tid] = v;
    __syncthreads();
#pragma unroll
    for (int off = 1; off < 256; off <<= 1) {
        int t = (tid >= off) ? scan[tid - off] : 0;
        __syncthreads();
        scan[tid] += t;
        __syncthreads();
    }
    int excl = scan[tid] - v;
    int n = nbase + tid;
    if (tid < 128 && n < N) row_ptr[n] = gB + excl;
    cur[tid] = gB + excl;
    __syncthreads();
    for (int e = gB + tid; e < gEnd; e += 256) {
        unsigned int pv = ebuf[e];
        int s = (int)(pv & 0xFFFFu);
        int d = (int)(pv >> 16);
        int p = atomicAdd(&cur[d - nbase], 1);
        col[p] = s;
    }
}

// ------------------------------ aggregation --------------------------------
// one wave per node. 4-way split: quarter=lane>>4 takes every 4th neighbor,
// lane loads ushort8 (16B, 8 features; li=lane&15 covers 128). Unroll 2 ->
// up to 4 independent row-loads in flight per lane. Cross-quarter combine
// via shfl_down(16) + shfl_down(32). Output: mean hi only.
__global__ __launch_bounds__(256) void agg_mean_kernel(
    const unsigned short* __restrict__ inH,
    const int* __restrict__ row_ptr, const int* __restrict__ col,
    unsigned short* __restrict__ mH, int N) {
    int wave = threadIdx.x >> 6;
    int lane = threadIdx.x & 63;
    int n = blockIdx.x * 4 + wave;
    if (n >= N) return;
    int quarter = lane >> 4;
    int li = lane & 15;
    int beg = row_ptr[n];
    int end = row_ptr[n + 1];
    float a0 = 0.f, a1 = 0.f, a2 = 0.f, a3 = 0.f;
    float a4 = 0.f, a5 = 0.f, a6 = 0.f, a7 = 0.f;
    float b0 = 0.f, b1 = 0.f, b2 = 0.f, b3 = 0.f;
    float b4 = 0.f, b5 = 0.f, b6 = 0.f, b7 = 0.f;
    int i = beg + quarter;
    for (; i + 4 < end; i += 8) {
        int s0 = col[i], s1 = col[i + 4];
        ushort8 h0 = ((const ushort8*)(inH + (size_t)s0 * 128))[li];
        ushort8 h1 = ((const ushort8*)(inH + (size_t)s1 * 128))[li];
        a0 += bf2f(h0[0]); a1 += bf2f(h0[1]); a2 += bf2f(h0[2]); a3 += bf2f(h0[3]);
        a4 += bf2f(h0[4]); a5 += bf2f(h0[5]); a6 += bf2f(h0[6]); a7 += bf2f(h0[7]);
        b0 += bf2f(h1[0]); b1 += bf2f(h1[1]); b2 += bf2f(h1[2]); b3 += bf2f(h1[3]);
        b4 += bf2f(h1[4]); b5 += bf2f(h1[5]); b6 += bf2f(h1[6]); b7 += bf2f(h1[7]);
    }
    for (; i < end; i += 4) {
        int s0 = col[i];
        ushort8 h0 = ((const ushort8*)(inH + (size_t)s0 * 128))[li];
        a0 += bf2f(h0[0]); a1 += bf2f(h0[1]); a2 += bf2f(h0[2]); a3 += bf2f(h0[3]);
        a4 += bf2f(h0[4]); a5 += bf2f(h0[5]); a6 += bf2f(h0[6]); a7 += bf2f(h0[7]);
    }
    a0 += b0; a1 += b1; a2 += b2; a3 += b3;
    a4 += b4; a5 += b5; a6 += b6; a7 += b7;
    a0 += __shfl_down(a0, 16); a1 += __shfl_down(a1, 16);
    a2 += __shfl_down(a2, 16); a3 += __shfl_down(a3, 16);
    a4 += __shfl_down(a4, 16); a5 += __shfl_down(a5, 16);
    a6 += __shfl_down(a6, 16); a7 += __shfl_down(a7, 16);
    a0 += __shfl_down(a0, 32); a1 += __shfl_down(a1, 32);
    a2 += __shfl_down(a2, 32); a3 += __shfl_down(a3, 32);
    a4 += __shfl_down(a4, 32); a5 += __shfl_down(a5, 32);
    a6 += __shfl_down(a6, 32); a7 += __shfl_down(a7, 32);
    if (quarter == 0) {
        int d = end - beg;
        float inv = 1.0f / (float)(d > 0 ? d : 1);
        ushort8 o;
        o[0] = (unsigned short)(__float_as_uint(a0 * inv) >> 16);
        o[1] = (unsigned short)(__float_as_uint(a1 * inv) >> 16);
        o[2] = (unsigned short)(__float_as_uint(a2 * inv) >> 16);
        o[3] = (unsigned short)(__float_as_uint(a3 * inv) >> 16);
        o[4] = (unsigned short)(__float_as_uint(a4 * inv) >> 16);
        o[5] = (unsigned short)(__float_as_uint(a5 * inv) >> 16);
        o[6] = (unsigned short)(__float_as_uint(a6 * inv) >> 16);
        o[7] = (unsigned short)(__float_as_uint(a7 * inv) >> 16);
        ((ushort8*)(mH + (size_t)n * 128))[li] = o;
    }
}

// ------------------------- split-bf16 MFMA GEMM ----------------------------
// out[n][j] = ReLU( mean[n]@Wl[j] + x[n]@Wr[j] + bias[j] )
// part0: mean hi-only (2 MFMA/k-step); part1: x hi+lo (3 MFMA/k-step).
__global__ __launch_bounds__(256, 2) void sage_gemm_mfma(
    const unsigned short* __restrict__ a0H,
    const unsigned short* __restrict__ a1H, const unsigned short* __restrict__ a1L,
    const unsigned short* __restrict__ wlH, const unsigned short* __restrict__ wlL,
    const unsigned short* __restrict__ wrH, const unsigned short* __restrict__ wrL,
    const float* __restrict__ bias,
    unsigned short* __restrict__ outH, unsigned short* __restrict__ outL, int N) {
    __shared__ unsigned short Ah[128][40];
    __shared__ unsigned short Al[128][40];
    __shared__ unsigned short Wh[128][40];
    __shared__ unsigned short Wl[128][40];
    int tid = threadIdx.x;
    int n0 = blockIdx.x * 128;
    int wv = tid >> 6, lane = tid & 63;
    int wm = wv & 1, wn = wv >> 1;
    int r16 = lane & 15, q = lane >> 4, q8 = q * 8;

    floatx4 acc[4][4];
#pragma unroll
    for (int mi = 0; mi < 4; ++mi)
#pragma unroll
        for (int ni = 0; ni < 4; ++ni) {
            floatx4 z = {0.f, 0.f, 0.f, 0.f};
            acc[mi][ni] = z;
        }

    int tc = (tid & 3) * 8;
    int tr = tid >> 2;

    // ---- part 0: mean(hi) @ Wl ----
    for (int kk = 0; kk < 128; kk += 32) {
        __syncthreads();
#pragma unroll
        for (int rr = 0; rr < 2; ++rr) {
            int row = tr + 64 * rr;
            int n = n0 + row;
            ushort8 vh = {0, 0, 0, 0, 0, 0, 0, 0};
            if (n < N) vh = *(const ushort8*)&a0H[(size_t)n * 128 + kk + tc];
            *(ushort8*)&Ah[row][tc] = vh;
            *(ushort8*)&Wh[row][tc] = *(const ushort8*)&wlH[(size_t)row * 128 + kk + tc];
            *(ushort8*)&Wl[row][tc] = *(const ushort8*)&wlL[(size_t)row * 128 + kk + tc];
        }
        __syncthreads();
        short8 am[4];
#pragma unroll
        for (int mi = 0; mi < 4; ++mi)
            am[mi] = *(const short8*)&Ah[64 * wm + 16 * mi + r16][q8];
#pragma unroll
        for (int ni = 0; ni < 4; ++ni) {
            int row = 64 * wn + 16 * ni + r16;
            short8 bh = *(const short8*)&Wh[row][q8];
            short8 bl = *(const short8*)&Wl[row][q8];
#pragma unroll
            for (int mi = 0; mi < 4; ++mi) {
                acc[mi][ni] = __builtin_amdgcn_mfma_f32_16x16x32_bf16(am[mi], bh, acc[mi][ni], 0, 0, 0);
                acc[mi][ni] = __builtin_amdgcn_mfma_f32_16x16x32_bf16(am[mi], bl, acc[mi][ni], 0, 0, 0);
            }
        }
    }

    // ---- part 1: x(hi+lo) @ Wr ----
    for (int kk = 0; kk < 128; kk += 32) {
        __syncthreads();
#pragma unroll
        for (int rr = 0; rr < 2; ++rr) {
            int row = tr + 64 * rr;
            int n = n0 + row;
            ushort8 vh = {0, 0, 0, 0, 0, 0, 0, 0};
            ushort8 vl = {0, 0, 0, 0, 0, 0, 0, 0};
            if (n < N) {
                vh = *(const ushort8*)&a1H[(size_t)n * 128 + kk + tc];
                vl = *(const ushort8*)&a1L[(size_t)n * 128 + kk + tc];
            }
            *(ushort8*)&Ah[row][tc] = vh;
            *(ushort8*)&Al[row][tc] = vl;
            *(ushort8*)&Wh[row][tc] = *(const ushort8*)&wrH[(size_t)row * 128 + kk + tc];
            *(ushort8*)&Wl[row][tc] = *(const ushort8*)&wrL[(size_t)row * 128 + kk + tc];
        }
        __syncthreads();
        short8 ah[4], al[4];
#pragma unroll
        for (int mi = 0; mi < 4; ++mi) {
            int row = 64 * wm + 16 * mi + r16;
            ah[mi] = *(const short8*)&Ah[row][q8];
            al[mi] = *(const short8*)&Al[row][q8];
        }
#pragma unroll
        for (int ni = 0; ni < 4; ++ni) {
            int row = 64 * wn + 16 * ni + r16;
            short8 bh = *(const short8*)&Wh[row][q8];
            short8 bl = *(const short8*)&Wl[row][q8];
#pragma unroll
            for (int mi = 0; mi < 4; ++mi) {
                acc[mi][ni] = __builtin_amdgcn_mfma_f32_16x16x32_bf16(ah[mi], bh, acc[mi][ni], 0, 0, 0);
                acc[mi][ni] = __builtin_amdgcn_mfma_f32_16x16x32_bf16(al[mi], bh, acc[mi][ni], 0, 0, 0);
                acc[mi][ni] = __builtin_amdgcn_mfma_f32_16x16x32_bf16(ah[mi], bl, acc[mi][ni], 0, 0, 0);
            }
        }
    }

    // ---- epilogue ----
#pragma unroll
    for (int ni = 0; ni < 4; ++ni) {
        int j = 64 * wn + 16 * ni + r16;
        float b = bias[j];
#pragma unroll
        for (int mi = 0; mi < 4; ++mi) {
            floatx4 v = acc[mi][ni];
#pragma unroll
            for (int p = 0; p < 4; ++p) {
                int node = n0 + 64 * wm + 16 * mi + 4 * q + p;
                if (node < N) {
                    float val = fmaxf(v[p] + b, 0.f);
                    unsigned short hi, lo;
                    split2(val, hi, lo);
                    outH[(size_t)node * 128 + j] = hi;
                    outL[(size_t)node * 128 + j] = lo;
                }
            }
        }
    }
}

// ------------------------------ fused head ---------------------------------

__global__ __launch_bounds__(256) void head_fused_kernel(
    const unsigned short* __restrict__ hH, const unsigned short* __restrict__ hL,
    const float* __restrict__ Wh1, const float* __restrict__ bh1,
    const float* __restrict__ Wh2, const float* __restrict__ bh2,
    float* __restrict__ out, int N) {
    __shared__ float As[64][33];
    __shared__ float Bs[32][65];
    __shared__ float Hs[64][65];
    int tid = threadIdx.x;
    int n0 = blockIdx.x * 64;
    int ti = tid & 15;
    int tj = tid >> 4;

    float acc[4][4];
#pragma unroll
    for (int r = 0; r < 4; ++r)
#pragma unroll
        for (int c = 0; c < 4; ++c) acc[r][c] = 0.f;

    for (int kk = 0; kk < 128; kk += 32) {
        int ks = tid & 31, i0 = tid >> 5;
#pragma unroll
        for (int r = 0; r < 8; ++r) {
            int i = i0 + 8 * r;
            int n = n0 + i;
            As[i][ks] = (n < N)
                ? (bf2f(hH[(size_t)n * 128 + kk + ks]) + bf2f(hL[(size_t)n * 128 + kk + ks]))
                : 0.f;
        }
        int jj0 = tid >> 5;
#pragma unroll
        for (int r = 0; r < 8; ++r) {
            int j = jj0 + 8 * r;
            Bs[ks][j] = Wh1[(size_t)j * 128 + kk + ks];
        }
        __syncthreads();
#pragma unroll 4
        for (int k = 0; k < 32; ++k) {
            float4 b = *(const float4*)&Bs[k][4 * tj];
#pragma unroll
            for (int r = 0; r < 4; ++r) {
                float a = As[4 * ti + r][k];
                acc[r][0] += a * b.x; acc[r][1] += a * b.y;
                acc[r][2] += a * b.z; acc[r][3] += a * b.w;
            }
        }
        __syncthreads();
    }
    float4 bv = *(const float4*)&bh1[4 * tj];
#pragma unroll
    for (int r = 0; r < 4; ++r) {
        int i = 4 * ti + r;
        Hs[i][4 * tj + 0] = fmaxf(acc[r][0] + bv.x, 0.f);
        Hs[i][4 * tj + 1] = fmaxf(acc[r][1] + bv.y, 0.f);
        Hs[i][4 * tj + 2] = fmaxf(acc[r][2] + bv.z, 0.f);
        Hs[i][4 * tj + 3] = fmaxf(acc[r][3] + bv.w, 0.f);
    }
    __syncthreads();
    int ni = tid >> 2;
    int c = tid & 3;
    const float* w = Wh2 + (size_t)c * 64;
    float s = bh2[c];
#pragma unroll 8
    for (int k = 0; k < 64; ++k) s += Hs[ni][k] * w[k];
    int n = n0 + ni;
    if (n < N) out[(size_t)n * 4 + c] = s;
}

// ------------------------------- launcher ----------------------------------

extern "C" void kernel_launch(void* const* d_in, const int* in_sizes, int n_in,
                              void* d_out, int out_size, void* d_ws, size_t ws_size,
                              hipStream_t stream) {
    const float* x   = (const float*)d_in[0];
    const int*   ei  = (const int*)d_in[1];
    const float* Wl0 = (const float*)d_in[2];
    const float* bl0 = (const float*)d_in[3];
    const float* Wr0 = (const float*)d_in[4];
    const float* Wl1 = (const float*)d_in[5];
    const float* bl1 = (const float*)d_in[6];
    const float* Wr1 = (const float*)d_in[7];
    const float* Wl2 = (const float*)d_in[8];
    const float* bl2 = (const float*)d_in[9];
    const float* Wr2 = (const float*)d_in[10];
    const float* Wh1 = (const float*)d_in[11];
    const float* bh1 = (const float*)d_in[12];
    const float* Wh2 = (const float*)d_in[13];
    const float* bh2 = (const float*)d_in[14];
    float* out = (float*)d_out;

    const int N = in_sizes[0] / 128;
    const int E = in_sizes[1] / 2;
    const int* src = ei;
    const int* dst = ei + E;
    const int NBUCK = ((N + 127) >> BSHIFT);

    int* row_ptr       = (int*)d_ws;                 // N+1
    int* bh            = row_ptr + N + 1;            // NBUCK
    int* bucket_base   = bh + NBUCK;                 // NBUCK+1
    int* bucket_cursor = bucket_base + NBUCK + 1;    // NBUCK
    unsigned int* ebuf = (unsigned int*)(bucket_cursor + NBUCK);  // E
    int* col           = (int*)(ebuf + E);           // E
    size_t ioff = (((size_t)(N + 1 + 3 * NBUCK + 1 + 2 * (size_t)E)) * sizeof(int) + 255) & ~(size_t)255;
    unsigned short* u0H = (unsigned short*)((char*)d_ws + ioff);  // x / hB pairs
    unsigned short* u0L = u0H + (size_t)N * 128;
    unsigned short* mHb = u0L + (size_t)N * 128;                  // mean hi
    unsigned short* aH  = mHb + (size_t)N * 128;                  // hA pairs
    unsigned short* aL  = aH + (size_t)N * 128;
    unsigned short* WH  = aL + (size_t)N * 128;                   // 6 x 16384
    unsigned short* WL  = WH + 6 * 16384;

    const int nb4 = (N + 3) / 4;
    const int gb64 = (N + 63) / 64;
    const int gb128 = (N + 127) / 128;
    const int CHUNK = 2048;
    const int nchunk = (E + CHUNK - 1) / CHUNK;
    const int XB = (N * 32 + 255) / 256;
    const int WB = 96;
    const int HB = 256;

    // CSR build + conversions
    hipMemsetAsync(bh, 0, (size_t)NBUCK * sizeof(int), stream);
    prep_kernel<<<XB + WB + HB, 256, 0, stream>>>(x, u0H, u0L, N * 32,
                                                  Wl0, Wr0, Wl1, Wr1, Wl2, Wr2,
                                                  WH, WL, dst, E, bh, NBUCK, XB, WB, HB);
    bucket_scan_kernel<<<1, 512, 0, stream>>>(bh, bucket_base, bucket_cursor, row_ptr, NBUCK, N, E);
    binsort_kernel<<<nchunk, 256, 0, stream>>>(src, dst, E, CHUNK, bucket_cursor, ebuf, NBUCK);
    bucket_fill_kernel<<<NBUCK, 256, 0, stream>>>(bucket_base, ebuf, row_ptr, col, N);

    // layer 0
    agg_mean_kernel<<<nb4, 256, 0, stream>>>(u0H, row_ptr, col, mHb, N);
    sage_gemm_mfma<<<gb128, 256, 0, stream>>>(mHb, u0H, u0L,
                                              WH + 0 * 16384, WL + 0 * 16384,
                                              WH + 1 * 16384, WL + 1 * 16384,
                                              bl0, aH, aL, N);
    // layer 1
    agg_mean_kernel<<<nb4, 256, 0, stream>>>(aH, row_ptr, col, mHb, N);
    sage_gemm_mfma<<<gb128, 256, 0, stream>>>(mHb, aH, aL,
                                              WH + 2 * 16384, WL + 2 * 16384,
                                              WH + 3 * 16384, WL + 3 * 16384,
                                              bl1, u0H, u0L, N);
    // layer 2
    agg_mean_kernel<<<nb4, 256, 0, stream>>>(u0H, row_ptr, col, mHb, N);
    sage_gemm_mfma<<<gb128, 256, 0, stream>>>(mHb, u0H, u0L,
                                              WH + 4 * 16384, WL + 4 * 16384,
                                              WH + 5 * 16384, WL + 5 * 16384,
                                              bl2, aH, aL, N);

    // fused head MLP
    head_fused_kernel<<<gb64, 256, 0, stream>>>(aH, aL, Wh1, bh1, Wh2, bh2, out, N);
}

// Round 12
// 317.559 us; speedup vs baseline: 2.0565x; 1.0527x over previous
//
#include <hip/hip_runtime.h>
#include <cstdint>
#include <cstddef>

// ---------------------------------------------------------------------------
// StationGNN: 3x GraphSAGE(mean) + MLP head.
// R1 fused head; R2 parallel scan; R3 split-bf16 MFMA; R4 hi-only gather;
// R5-R7 counting-sort CSR; R8 separated structure; R9 fusion FAILED (revert);
// R10 hi-only mean + half-split gather; R11 4-way-split gather (334us).
// R12: activations stored hi-only EVERYWHERE (absmax pinned at 1 bf16
//      half-ULP floor across R4-R11 => activation-lo is below the noise
//      floor). Weights keep hi+lo. GEMM: 4 MFMA/k-step (was 5), 3 LDS
//      staging arrays (was 4), epilogue writes halved, prep/head halved.
// ---------------------------------------------------------------------------

typedef __attribute__((ext_vector_type(8))) short short8;
typedef __attribute__((ext_vector_type(8))) unsigned short ushort8;
typedef __attribute__((ext_vector_type(4))) float floatx4;

#define BSHIFT 7                 // 128 nodes per bucket
#define MAXB 512

__device__ __forceinline__ float bf2f(unsigned short h) {
    return __uint_as_float(((unsigned int)h) << 16);
}
__device__ __forceinline__ void split2(float x, unsigned short& hi, unsigned short& lo) {
    unsigned int u = __float_as_uint(x);
    hi = (unsigned short)(u >> 16);
    float r = x - __uint_as_float(u & 0xFFFF0000u);
    lo = (unsigned short)(__float_as_uint(r) >> 16);
}

// ------------------- prep: convert_x(hi) + convert_w + hist ----------------

__global__ __launch_bounds__(256) void prep_kernel(
    const float* __restrict__ x, unsigned short* __restrict__ xH, int total4,
    const float* __restrict__ w0, const float* __restrict__ w1,
    const float* __restrict__ w2, const float* __restrict__ w3,
    const float* __restrict__ w4, const float* __restrict__ w5,
    unsigned short* __restrict__ WH, unsigned short* __restrict__ WL,
    const int* __restrict__ dst, int E, int* __restrict__ bh, int NBUCK,
    int XB, int WB, int HB) {
    __shared__ int lh[MAXB];
    int bid = blockIdx.x;
    int tid = threadIdx.x;
    if (bid < XB) {
        int i = bid * 256 + tid;
        if (i < total4) {
            float4 v = ((const float4*)x)[i];
            ushort4 h;
            h.x = (unsigned short)(__float_as_uint(v.x) >> 16);
            h.y = (unsigned short)(__float_as_uint(v.y) >> 16);
            h.z = (unsigned short)(__float_as_uint(v.z) >> 16);
            h.w = (unsigned short)(__float_as_uint(v.w) >> 16);
            ((ushort4*)xH)[i] = h;
        }
    } else if (bid < XB + WB) {
        int wb = bid - XB;
        int m = wb >> 4;
        const float* src = (m == 0) ? w0 : (m == 1) ? w1 : (m == 2) ? w2
                           : (m == 3) ? w3 : (m == 4) ? w4 : w5;
        int i = ((wb & 15) << 8) + tid;   // 4096 float4 per matrix
        float4 v = ((const float4*)src)[i];
        unsigned short h0, h1, h2, h3, l0, l1, l2, l3;
        split2(v.x, h0, l0); split2(v.y, h1, l1);
        split2(v.z, h2, l2); split2(v.w, h3, l3);
        ((ushort4*)(WH + (size_t)m * 16384))[i] = make_ushort4(h0, h1, h2, h3);
        ((ushort4*)(WL + (size_t)m * 16384))[i] = make_ushort4(l0, l1, l2, l3);
    } else {
        int hbid = bid - XB - WB;
        for (int i = tid; i < NBUCK; i += 256) lh[i] = 0;
        __syncthreads();
        for (int e = hbid * 256 + tid; e < E; e += HB * 256)
            atomicAdd(&lh[dst[e] >> BSHIFT], 1);
        __syncthreads();
        for (int i = tid; i < NBUCK; i += 256)
            if (lh[i]) atomicAdd(&bh[i], lh[i]);
    }
}

// -------------------- bucket scan (one block, parallel) --------------------

__global__ __launch_bounds__(512) void bucket_scan_kernel(const int* __restrict__ bh,
                                                          int* __restrict__ bucket_base,
                                                          int* __restrict__ bucket_cursor,
                                                          int* __restrict__ row_ptr,
                                                          int NBUCK, int N, int E) {
    __shared__ int s[512];
    int tid = threadIdx.x;
    int v = (tid < NBUCK) ? bh[tid] : 0;
    s[tid] = v;
    __syncthreads();
#pragma unroll
    for (int off = 1; off < 512; off <<= 1) {
        int t = (tid >= off) ? s[tid - off] : 0;
        __syncthreads();
        s[tid] += t;
        __syncthreads();
    }
    int excl = s[tid] - v;
    if (tid < NBUCK) { bucket_base[tid] = excl; bucket_cursor[tid] = excl; }
    if (tid == 0) { bucket_base[NBUCK] = E; row_ptr[N] = E; }
}

// ------------------------------- binsort -----------------------------------

__global__ __launch_bounds__(256) void binsort_kernel(const int* __restrict__ src,
                                                      const int* __restrict__ dst,
                                                      int E, int CHUNK,
                                                      int* __restrict__ bucket_cursor,
                                                      unsigned int* __restrict__ ebuf,
                                                      int NBUCK) {
    __shared__ int lh[MAXB];
    __shared__ int lcur[MAXB];
    __shared__ int gbase[MAXB];
    int e0 = blockIdx.x * CHUNK;
    int e1 = e0 + CHUNK; if (e1 > E) e1 = E;
    for (int i = threadIdx.x; i < NBUCK; i += 256) { lh[i] = 0; lcur[i] = 0; }
    __syncthreads();
    for (int e = e0 + threadIdx.x; e < e1; e += 256)
        atomicAdd(&lh[dst[e] >> BSHIFT], 1);
    __syncthreads();
    for (int b = threadIdx.x; b < NBUCK; b += 256) {
        int c = lh[b];
        gbase[b] = c ? atomicAdd(&bucket_cursor[b], c) : 0;
    }
    __syncthreads();
    for (int e = e0 + threadIdx.x; e < e1; e += 256) {
        int d = dst[e];
        int s = src[e];
        int b = d >> BSHIFT;
        int off = atomicAdd(&lcur[b], 1);
        ebuf[gbase[b] + off] = (unsigned int)s | ((unsigned int)d << 16);
    }
}

// ----------------------------- bucket fill ---------------------------------

__global__ __launch_bounds__(256) void bucket_fill_kernel(const int* __restrict__ bucket_base,
                                                          const unsigned int* __restrict__ ebuf,
                                                          int* __restrict__ row_ptr,
                                                          int* __restrict__ col, int N) {
    __shared__ int cnt[256];
    __shared__ int scan[256];
    __shared__ int cur[256];
    int b = blockIdx.x;
    int nbase = b << BSHIFT;
    int tid = threadIdx.x;
    int gB = bucket_base[b];
    int gEnd = bucket_base[b + 1];
    cnt[tid] = 0;
    __syncthreads();
    for (int e = gB + tid; e < gEnd; e += 256)
        atomicAdd(&cnt[(ebuf[e] >> 16) - nbase], 1);
    __syncthreads();
    int v = cnt[tid];
    scan[tid] = v;
    __syncthreads();
#pragma unroll
    for (int off = 1; off < 256; off <<= 1) {
        int t = (tid >= off) ? scan[tid - off] : 0;
        __syncthreads();
        scan[tid] += t;
        __syncthreads();
    }
    int excl = scan[tid] - v;
    int n = nbase + tid;
    if (tid < 128 && n < N) row_ptr[n] = gB + excl;
    cur[tid] = gB + excl;
    __syncthreads();
    for (int e = gB + tid; e < gEnd; e += 256) {
        unsigned int pv = ebuf[e];
        int s = (int)(pv & 0xFFFFu);
        int d = (int)(pv >> 16);
        int p = atomicAdd(&cur[d - nbase], 1);
        col[p] = s;
    }
}

// ------------------------------ aggregation --------------------------------
// one wave per node; 4-way neighbor split; lane loads ushort8 (16B).

__global__ __launch_bounds__(256) void agg_mean_kernel(
    const unsigned short* __restrict__ inH,
    const int* __restrict__ row_ptr, const int* __restrict__ col,
    unsigned short* __restrict__ mH, int N) {
    int wave = threadIdx.x >> 6;
    int lane = threadIdx.x & 63;
    int n = blockIdx.x * 4 + wave;
    if (n >= N) return;
    int quarter = lane >> 4;
    int li = lane & 15;
    int beg = row_ptr[n];
    int end = row_ptr[n + 1];
    float a0 = 0.f, a1 = 0.f, a2 = 0.f, a3 = 0.f;
    float a4 = 0.f, a5 = 0.f, a6 = 0.f, a7 = 0.f;
    float b0 = 0.f, b1 = 0.f, b2 = 0.f, b3 = 0.f;
    float b4 = 0.f, b5 = 0.f, b6 = 0.f, b7 = 0.f;
    int i = beg + quarter;
    for (; i + 4 < end; i += 8) {
        int s0 = col[i], s1 = col[i + 4];
        ushort8 h0 = ((const ushort8*)(inH + (size_t)s0 * 128))[li];
        ushort8 h1 = ((const ushort8*)(inH + (size_t)s1 * 128))[li];
        a0 += bf2f(h0[0]); a1 += bf2f(h0[1]); a2 += bf2f(h0[2]); a3 += bf2f(h0[3]);
        a4 += bf2f(h0[4]); a5 += bf2f(h0[5]); a6 += bf2f(h0[6]); a7 += bf2f(h0[7]);
        b0 += bf2f(h1[0]); b1 += bf2f(h1[1]); b2 += bf2f(h1[2]); b3 += bf2f(h1[3]);
        b4 += bf2f(h1[4]); b5 += bf2f(h1[5]); b6 += bf2f(h1[6]); b7 += bf2f(h1[7]);
    }
    for (; i < end; i += 4) {
        int s0 = col[i];
        ushort8 h0 = ((const ushort8*)(inH + (size_t)s0 * 128))[li];
        a0 += bf2f(h0[0]); a1 += bf2f(h0[1]); a2 += bf2f(h0[2]); a3 += bf2f(h0[3]);
        a4 += bf2f(h0[4]); a5 += bf2f(h0[5]); a6 += bf2f(h0[6]); a7 += bf2f(h0[7]);
    }
    a0 += b0; a1 += b1; a2 += b2; a3 += b3;
    a4 += b4; a5 += b5; a6 += b6; a7 += b7;
    a0 += __shfl_down(a0, 16); a1 += __shfl_down(a1, 16);
    a2 += __shfl_down(a2, 16); a3 += __shfl_down(a3, 16);
    a4 += __shfl_down(a4, 16); a5 += __shfl_down(a5, 16);
    a6 += __shfl_down(a6, 16); a7 += __shfl_down(a7, 16);
    a0 += __shfl_down(a0, 32); a1 += __shfl_down(a1, 32);
    a2 += __shfl_down(a2, 32); a3 += __shfl_down(a3, 32);
    a4 += __shfl_down(a4, 32); a5 += __shfl_down(a5, 32);
    a6 += __shfl_down(a6, 32); a7 += __shfl_down(a7, 32);
    if (quarter == 0) {
        int d = end - beg;
        float inv = 1.0f / (float)(d > 0 ? d : 1);
        ushort8 o;
        o[0] = (unsigned short)(__float_as_uint(a0 * inv) >> 16);
        o[1] = (unsigned short)(__float_as_uint(a1 * inv) >> 16);
        o[2] = (unsigned short)(__float_as_uint(a2 * inv) >> 16);
        o[3] = (unsigned short)(__float_as_uint(a3 * inv) >> 16);
        o[4] = (unsigned short)(__float_as_uint(a4 * inv) >> 16);
        o[5] = (unsigned short)(__float_as_uint(a5 * inv) >> 16);
        o[6] = (unsigned short)(__float_as_uint(a6 * inv) >> 16);
        o[7] = (unsigned short)(__float_as_uint(a7 * inv) >> 16);
        ((ushort8*)(mH + (size_t)n * 128))[li] = o;
    }
}

// ------------------------- split-bf16 MFMA GEMM ----------------------------
// out[n][j] = ReLU( mean[n]@Wl[j] + x[n]@Wr[j] + bias[j] )
// Activations hi-only; weights hi+lo. 2 MFMA per k-step per part (a*wh + a*wl).
__global__ __launch_bounds__(256, 2) void sage_gemm_mfma(
    const unsigned short* __restrict__ a0H, const unsigned short* __restrict__ a1H,
    const unsigned short* __restrict__ wlH, const unsigned short* __restrict__ wlL,
    const unsigned short* __restrict__ wrH, const unsigned short* __restrict__ wrL,
    const float* __restrict__ bias,
    unsigned short* __restrict__ outH, int N) {
    __shared__ unsigned short Ah[128][40];
    __shared__ unsigned short Wh[128][40];
    __shared__ unsigned short Wl[128][40];
    int tid = threadIdx.x;
    int n0 = blockIdx.x * 128;
    int wv = tid >> 6, lane = tid & 63;
    int wm = wv & 1, wn = wv >> 1;
    int r16 = lane & 15, q = lane >> 4, q8 = q * 8;

    floatx4 acc[4][4];
#pragma unroll
    for (int mi = 0; mi < 4; ++mi)
#pragma unroll
        for (int ni = 0; ni < 4; ++ni) {
            floatx4 z = {0.f, 0.f, 0.f, 0.f};
            acc[mi][ni] = z;
        }

    int tc = (tid & 3) * 8;
    int tr = tid >> 2;

    for (int part = 0; part < 2; ++part) {
        const unsigned short* AH = part ? a1H : a0H;
        const unsigned short* WHp = part ? wrH : wlH;
        const unsigned short* WLp = part ? wrL : wlL;
        for (int kk = 0; kk < 128; kk += 32) {
            __syncthreads();
#pragma unroll
            for (int rr = 0; rr < 2; ++rr) {
                int row = tr + 64 * rr;
                int n = n0 + row;
                ushort8 vh = {0, 0, 0, 0, 0, 0, 0, 0};
                if (n < N) vh = *(const ushort8*)&AH[(size_t)n * 128 + kk + tc];
                *(ushort8*)&Ah[row][tc] = vh;
                *(ushort8*)&Wh[row][tc] = *(const ushort8*)&WHp[(size_t)row * 128 + kk + tc];
                *(ushort8*)&Wl[row][tc] = *(const ushort8*)&WLp[(size_t)row * 128 + kk + tc];
            }
            __syncthreads();
            short8 ah[4];
#pragma unroll
            for (int mi = 0; mi < 4; ++mi)
                ah[mi] = *(const short8*)&Ah[64 * wm + 16 * mi + r16][q8];
#pragma unroll
            for (int ni = 0; ni < 4; ++ni) {
                int row = 64 * wn + 16 * ni + r16;
                short8 bh = *(const short8*)&Wh[row][q8];
                short8 bl = *(const short8*)&Wl[row][q8];
#pragma unroll
                for (int mi = 0; mi < 4; ++mi) {
                    acc[mi][ni] = __builtin_amdgcn_mfma_f32_16x16x32_bf16(ah[mi], bh, acc[mi][ni], 0, 0, 0);
                    acc[mi][ni] = __builtin_amdgcn_mfma_f32_16x16x32_bf16(ah[mi], bl, acc[mi][ni], 0, 0, 0);
                }
            }
        }
    }

    // epilogue: bias + ReLU -> bf16 hi only
#pragma unroll
    for (int ni = 0; ni < 4; ++ni) {
        int j = 64 * wn + 16 * ni + r16;
        float b = bias[j];
#pragma unroll
        for (int mi = 0; mi < 4; ++mi) {
            floatx4 v = acc[mi][ni];
#pragma unroll
            for (int p = 0; p < 4; ++p) {
                int node = n0 + 64 * wm + 16 * mi + 4 * q + p;
                if (node < N) {
                    float val = fmaxf(v[p] + b, 0.f);
                    outH[(size_t)node * 128 + j] =
                        (unsigned short)(__float_as_uint(val) >> 16);
                }
            }
        }
    }
}

// ------------------------------ fused head ---------------------------------

__global__ __launch_bounds__(256) void head_fused_kernel(
    const unsigned short* __restrict__ hH,
    const float* __restrict__ Wh1, const float* __restrict__ bh1,
    const float* __restrict__ Wh2, const float* __restrict__ bh2,
    float* __restrict__ out, int N) {
    __shared__ float As[64][33];
    __shared__ float Bs[32][65];
    __shared__ float Hs[64][65];
    int tid = threadIdx.x;
    int n0 = blockIdx.x * 64;
    int ti = tid & 15;
    int tj = tid >> 4;

    float acc[4][4];
#pragma unroll
    for (int r = 0; r < 4; ++r)
#pragma unroll
        for (int c = 0; c < 4; ++c) acc[r][c] = 0.f;

    for (int kk = 0; kk < 128; kk += 32) {
        int ks = tid & 31, i0 = tid >> 5;
#pragma unroll
        for (int r = 0; r < 8; ++r) {
            int i = i0 + 8 * r;
            int n = n0 + i;
            As[i][ks] = (n < N) ? bf2f(hH[(size_t)n * 128 + kk + ks]) : 0.f;
        }
        int jj0 = tid >> 5;
#pragma unroll
        for (int r = 0; r < 8; ++r) {
            int j = jj0 + 8 * r;
            Bs[ks][j] = Wh1[(size_t)j * 128 + kk + ks];
        }
        __syncthreads();
#pragma unroll 4
        for (int k = 0; k < 32; ++k) {
            float4 b = *(const float4*)&Bs[k][4 * tj];
#pragma unroll
            for (int r = 0; r < 4; ++r) {
                float a = As[4 * ti + r][k];
                acc[r][0] += a * b.x; acc[r][1] += a * b.y;
                acc[r][2] += a * b.z; acc[r][3] += a * b.w;
            }
        }
        __syncthreads();
    }
    float4 bv = *(const float4*)&bh1[4 * tj];
#pragma unroll
    for (int r = 0; r < 4; ++r) {
        int i = 4 * ti + r;
        Hs[i][4 * tj + 0] = fmaxf(acc[r][0] + bv.x, 0.f);
        Hs[i][4 * tj + 1] = fmaxf(acc[r][1] + bv.y, 0.f);
        Hs[i][4 * tj + 2] = fmaxf(acc[r][2] + bv.z, 0.f);
        Hs[i][4 * tj + 3] = fmaxf(acc[r][3] + bv.w, 0.f);
    }
    __syncthreads();
    int ni = tid >> 2;
    int c = tid & 3;
    const float* w = Wh2 + (size_t)c * 64;
    float s = bh2[c];
#pragma unroll 8
    for (int k = 0; k < 64; ++k) s += Hs[ni][k] * w[k];
    int n = n0 + ni;
    if (n < N) out[(size_t)n * 4 + c] = s;
}

// ------------------------------- launcher ----------------------------------

extern "C" void kernel_launch(void* const* d_in, const int* in_sizes, int n_in,
                              void* d_out, int out_size, void* d_ws, size_t ws_size,
                              hipStream_t stream) {
    const float* x   = (const float*)d_in[0];
    const int*   ei  = (const int*)d_in[1];
    const float* Wl0 = (const float*)d_in[2];
    const float* bl0 = (const float*)d_in[3];
    const float* Wr0 = (const float*)d_in[4];
    const float* Wl1 = (const float*)d_in[5];
    const float* bl1 = (const float*)d_in[6];
    const float* Wr1 = (const float*)d_in[7];
    const float* Wl2 = (const float*)d_in[8];
    const float* bl2 = (const float*)d_in[9];
    const float* Wr2 = (const float*)d_in[10];
    const float* Wh1 = (const float*)d_in[11];
    const float* bh1 = (const float*)d_in[12];
    const float* Wh2 = (const float*)d_in[13];
    const float* bh2 = (const float*)d_in[14];
    float* out = (float*)d_out;

    const int N = in_sizes[0] / 128;
    const int E = in_sizes[1] / 2;
    const int* src = ei;
    const int* dst = ei + E;
    const int NBUCK = ((N + 127) >> BSHIFT);

    int* row_ptr       = (int*)d_ws;                 // N+1
    int* bh            = row_ptr + N + 1;            // NBUCK
    int* bucket_base   = bh + NBUCK;                 // NBUCK+1
    int* bucket_cursor = bucket_base + NBUCK + 1;    // NBUCK
    unsigned int* ebuf = (unsigned int*)(bucket_cursor + NBUCK);  // E
    int* col           = (int*)(ebuf + E);           // E
    size_t ioff = (((size_t)(N + 1 + 3 * NBUCK + 1 + 2 * (size_t)E)) * sizeof(int) + 255) & ~(size_t)255;
    unsigned short* u0H = (unsigned short*)((char*)d_ws + ioff);  // x / hB hi
    unsigned short* mHb = u0H + (size_t)N * 128;                  // mean hi
    unsigned short* aH  = mHb + (size_t)N * 128;                  // hA hi
    unsigned short* WH  = aH + (size_t)N * 128;                   // 6 x 16384
    unsigned short* WL  = WH + 6 * 16384;

    const int nb4 = (N + 3) / 4;
    const int gb64 = (N + 63) / 64;
    const int gb128 = (N + 127) / 128;
    const int CHUNK = 2048;
    const int nchunk = (E + CHUNK - 1) / CHUNK;
    const int XB = (N * 32 + 255) / 256;
    const int WB = 96;
    const int HB = 256;

    // CSR build + conversions
    hipMemsetAsync(bh, 0, (size_t)NBUCK * sizeof(int), stream);
    prep_kernel<<<XB + WB + HB, 256, 0, stream>>>(x, u0H, N * 32,
                                                  Wl0, Wr0, Wl1, Wr1, Wl2, Wr2,
                                                  WH, WL, dst, E, bh, NBUCK, XB, WB, HB);
    bucket_scan_kernel<<<1, 512, 0, stream>>>(bh, bucket_base, bucket_cursor, row_ptr, NBUCK, N, E);
    binsort_kernel<<<nchunk, 256, 0, stream>>>(src, dst, E, CHUNK, bucket_cursor, ebuf, NBUCK);
    bucket_fill_kernel<<<NBUCK, 256, 0, stream>>>(bucket_base, ebuf, row_ptr, col, N);

    // layer 0
    agg_mean_kernel<<<nb4, 256, 0, stream>>>(u0H, row_ptr, col, mHb, N);
    sage_gemm_mfma<<<gb128, 256, 0, stream>>>(mHb, u0H,
                                              WH + 0 * 16384, WL + 0 * 16384,
                                              WH + 1 * 16384, WL + 1 * 16384,
                                              bl0, aH, N);
    // layer 1
    agg_mean_kernel<<<nb4, 256, 0, stream>>>(aH, row_ptr, col, mHb, N);
    sage_gemm_mfma<<<gb128, 256, 0, stream>>>(mHb, aH,
                                              WH + 2 * 16384, WL + 2 * 16384,
                                              WH + 3 * 16384, WL + 3 * 16384,
                                              bl1, u0H, N);
    // layer 2
    agg_mean_kernel<<<nb4, 256, 0, stream>>>(u0H, row_ptr, col, mHb, N);
    sage_gemm_mfma<<<gb128, 256, 0, stream>>>(mHb, u0H,
                                              WH + 4 * 16384, WL + 4 * 16384,
                                              WH + 5 * 16384, WL + 5 * 16384,
                                              bl2, aH, N);

    // fused head MLP
    head_fused_kernel<<<gb64, 256, 0, stream>>>(aH, Wh1, bh1, Wh2, bh2, out, N);
}

// Round 13
// 293.036 us; speedup vs baseline: 2.2286x; 1.0837x over previous
//
#include <hip/hip_runtime.h>
#include <cstdint>
#include <cstddef>

// ---------------------------------------------------------------------------
// StationGNN: 3x GraphSAGE(mean) + MLP head.
// R1 fused head; R2 parallel scan; R3 split-bf16 MFMA; R4 hi-only gather;
// R5-R7 counting-sort CSR; R8 separated structure; R9 fusion FAILED (revert);
// R10 hi-only mean; R11 4-way-split gather; R12 hi-only activations (317us,
// absmax pinned at the mean-path bf16 floor through all of it).
// R13: head MLP fused into the layer-2 GEMM epilogue: h round-trips LDS
//      (bf16, A-layout), head-1 done with MFMA vs Wh1(hi+lo), h1 in LDS,
//      64->4 tail as per-thread dots. Kills head dispatch + 25.6MB of
//      aH write/read traffic. Flat 52KB LDS overlays dead staging arrays.
// ---------------------------------------------------------------------------

typedef __attribute__((ext_vector_type(8))) short short8;
typedef __attribute__((ext_vector_type(8))) unsigned short ushort8;
typedef __attribute__((ext_vector_type(4))) float floatx4;

#define BSHIFT 7                 // 128 nodes per bucket
#define MAXB 512

__device__ __forceinline__ float bf2f(unsigned short h) {
    return __uint_as_float(((unsigned int)h) << 16);
}
__device__ __forceinline__ void split2(float x, unsigned short& hi, unsigned short& lo) {
    unsigned int u = __float_as_uint(x);
    hi = (unsigned short)(u >> 16);
    float r = x - __uint_as_float(u & 0xFFFF0000u);
    lo = (unsigned short)(__float_as_uint(r) >> 16);
}

// ---------- prep: convert_x(hi) + convert_w(6x128x128 + Wh1) + hist --------

__global__ __launch_bounds__(256) void prep_kernel(
    const float* __restrict__ x, unsigned short* __restrict__ xH, int total4,
    const float* __restrict__ w0, const float* __restrict__ w1,
    const float* __restrict__ w2, const float* __restrict__ w3,
    const float* __restrict__ w4, const float* __restrict__ w5,
    const float* __restrict__ wh1,
    unsigned short* __restrict__ WH, unsigned short* __restrict__ WL,
    const int* __restrict__ dst, int E, int* __restrict__ bh, int NBUCK,
    int XB, int WB, int HB) {
    __shared__ int lh[MAXB];
    int bid = blockIdx.x;
    int tid = threadIdx.x;
    if (bid < XB) {
        int i = bid * 256 + tid;
        if (i < total4) {
            float4 v = ((const float4*)x)[i];
            ushort4 h;
            h.x = (unsigned short)(__float_as_uint(v.x) >> 16);
            h.y = (unsigned short)(__float_as_uint(v.y) >> 16);
            h.z = (unsigned short)(__float_as_uint(v.z) >> 16);
            h.w = (unsigned short)(__float_as_uint(v.w) >> 16);
            ((ushort4*)xH)[i] = h;
        }
    } else if (bid < XB + WB) {
        int wb = bid - XB;
        if (wb < 96) {
            int m = wb >> 4;
            const float* src = (m == 0) ? w0 : (m == 1) ? w1 : (m == 2) ? w2
                               : (m == 3) ? w3 : (m == 4) ? w4 : w5;
            int i = ((wb & 15) << 8) + tid;   // 4096 float4 per matrix
            float4 v = ((const float4*)src)[i];
            unsigned short h0, h1, h2, h3, l0, l1, l2, l3;
            split2(v.x, h0, l0); split2(v.y, h1, l1);
            split2(v.z, h2, l2); split2(v.w, h3, l3);
            ((ushort4*)(WH + (size_t)m * 16384))[i] = make_ushort4(h0, h1, h2, h3);
            ((ushort4*)(WL + (size_t)m * 16384))[i] = make_ushort4(l0, l1, l2, l3);
        } else {
            int i = ((wb - 96) << 8) + tid;   // Wh1: 2048 float4 (64x128)
            if (i < 2048) {
                float4 v = ((const float4*)wh1)[i];
                unsigned short h0, h1, h2, h3, l0, l1, l2, l3;
                split2(v.x, h0, l0); split2(v.y, h1, l1);
                split2(v.z, h2, l2); split2(v.w, h3, l3);
                ((ushort4*)(WH + (size_t)6 * 16384))[i] = make_ushort4(h0, h1, h2, h3);
                ((ushort4*)(WL + (size_t)6 * 16384))[i] = make_ushort4(l0, l1, l2, l3);
            }
        }
    } else {
        int hbid = bid - XB - WB;
        for (int i = tid; i < NBUCK; i += 256) lh[i] = 0;
        __syncthreads();
        for (int e = hbid * 256 + tid; e < E; e += HB * 256)
            atomicAdd(&lh[dst[e] >> BSHIFT], 1);
        __syncthreads();
        for (int i = tid; i < NBUCK; i += 256)
            if (lh[i]) atomicAdd(&bh[i], lh[i]);
    }
}

// -------------------- bucket scan (one block, parallel) --------------------

__global__ __launch_bounds__(512) void bucket_scan_kernel(const int* __restrict__ bh,
                                                          int* __restrict__ bucket_base,
                                                          int* __restrict__ bucket_cursor,
                                                          int* __restrict__ row_ptr,
                                                          int NBUCK, int N, int E) {
    __shared__ int s[512];
    int tid = threadIdx.x;
    int v = (tid < NBUCK) ? bh[tid] : 0;
    s[tid] = v;
    __syncthreads();
#pragma unroll
    for (int off = 1; off < 512; off <<= 1) {
        int t = (tid >= off) ? s[tid - off] : 0;
        __syncthreads();
        s[tid] += t;
        __syncthreads();
    }
    int excl = s[tid] - v;
    if (tid < NBUCK) { bucket_base[tid] = excl; bucket_cursor[tid] = excl; }
    if (tid == 0) { bucket_base[NBUCK] = E; row_ptr[N] = E; }
}

// ------------------------------- binsort -----------------------------------

__global__ __launch_bounds__(256) void binsort_kernel(const int* __restrict__ src,
                                                      const int* __restrict__ dst,
                                                      int E, int CHUNK,
                                                      int* __restrict__ bucket_cursor,
                                                      unsigned int* __restrict__ ebuf,
                                                      int NBUCK) {
    __shared__ int lh[MAXB];
    __shared__ int lcur[MAXB];
    __shared__ int gbase[MAXB];
    int e0 = blockIdx.x * CHUNK;
    int e1 = e0 + CHUNK; if (e1 > E) e1 = E;
    for (int i = threadIdx.x; i < NBUCK; i += 256) { lh[i] = 0; lcur[i] = 0; }
    __syncthreads();
    for (int e = e0 + threadIdx.x; e < e1; e += 256)
        atomicAdd(&lh[dst[e] >> BSHIFT], 1);
    __syncthreads();
    for (int b = threadIdx.x; b < NBUCK; b += 256) {
        int c = lh[b];
        gbase[b] = c ? atomicAdd(&bucket_cursor[b], c) : 0;
    }
    __syncthreads();
    for (int e = e0 + threadIdx.x; e < e1; e += 256) {
        int d = dst[e];
        int s = src[e];
        int b = d >> BSHIFT;
        int off = atomicAdd(&lcur[b], 1);
        ebuf[gbase[b] + off] = (unsigned int)s | ((unsigned int)d << 16);
    }
}

// ----------------------------- bucket fill ---------------------------------

__global__ __launch_bounds__(256) void bucket_fill_kernel(const int* __restrict__ bucket_base,
                                                          const unsigned int* __restrict__ ebuf,
                                                          int* __restrict__ row_ptr,
                                                          int* __restrict__ col, int N) {
    __shared__ int cnt[256];
    __shared__ int scan[256];
    __shared__ int cur[256];
    int b = blockIdx.x;
    int nbase = b << BSHIFT;
    int tid = threadIdx.x;
    int gB = bucket_base[b];
    int gEnd = bucket_base[b + 1];
    cnt[tid] = 0;
    __syncthreads();
    for (int e = gB + tid; e < gEnd; e += 256)
        atomicAdd(&cnt[(ebuf[e] >> 16) - nbase], 1);
    __syncthreads();
    int v = cnt[tid];
    scan[tid] = v;
    __syncthreads();
#pragma unroll
    for (int off = 1; off < 256; off <<= 1) {
        int t = (tid >= off) ? scan[tid - off] : 0;
        __syncthreads();
        scan[tid] += t;
        __syncthreads();
    }
    int excl = scan[tid] - v;
    int n = nbase + tid;
    if (tid < 128 && n < N) row_ptr[n] = gB + excl;
    cur[tid] = gB + excl;
    __syncthreads();
    for (int e = gB + tid; e < gEnd; e += 256) {
        unsigned int pv = ebuf[e];
        int s = (int)(pv & 0xFFFFu);
        int d = (int)(pv >> 16);
        int p = atomicAdd(&cur[d - nbase], 1);
        col[p] = s;
    }
}

// ------------------------------ aggregation --------------------------------

__global__ __launch_bounds__(256) void agg_mean_kernel(
    const unsigned short* __restrict__ inH,
    const int* __restrict__ row_ptr, const int* __restrict__ col,
    unsigned short* __restrict__ mH, int N) {
    int wave = threadIdx.x >> 6;
    int lane = threadIdx.x & 63;
    int n = blockIdx.x * 4 + wave;
    if (n >= N) return;
    int quarter = lane >> 4;
    int li = lane & 15;
    int beg = row_ptr[n];
    int end = row_ptr[n + 1];
    float a0 = 0.f, a1 = 0.f, a2 = 0.f, a3 = 0.f;
    float a4 = 0.f, a5 = 0.f, a6 = 0.f, a7 = 0.f;
    float b0 = 0.f, b1 = 0.f, b2 = 0.f, b3 = 0.f;
    float b4 = 0.f, b5 = 0.f, b6 = 0.f, b7 = 0.f;
    int i = beg + quarter;
    for (; i + 4 < end; i += 8) {
        int s0 = col[i], s1 = col[i + 4];
        ushort8 h0 = ((const ushort8*)(inH + (size_t)s0 * 128))[li];
        ushort8 h1 = ((const ushort8*)(inH + (size_t)s1 * 128))[li];
        a0 += bf2f(h0[0]); a1 += bf2f(h0[1]); a2 += bf2f(h0[2]); a3 += bf2f(h0[3]);
        a4 += bf2f(h0[4]); a5 += bf2f(h0[5]); a6 += bf2f(h0[6]); a7 += bf2f(h0[7]);
        b0 += bf2f(h1[0]); b1 += bf2f(h1[1]); b2 += bf2f(h1[2]); b3 += bf2f(h1[3]);
        b4 += bf2f(h1[4]); b5 += bf2f(h1[5]); b6 += bf2f(h1[6]); b7 += bf2f(h1[7]);
    }
    for (; i < end; i += 4) {
        int s0 = col[i];
        ushort8 h0 = ((const ushort8*)(inH + (size_t)s0 * 128))[li];
        a0 += bf2f(h0[0]); a1 += bf2f(h0[1]); a2 += bf2f(h0[2]); a3 += bf2f(h0[3]);
        a4 += bf2f(h0[4]); a5 += bf2f(h0[5]); a6 += bf2f(h0[6]); a7 += bf2f(h0[7]);
    }
    a0 += b0; a1 += b1; a2 += b2; a3 += b3;
    a4 += b4; a5 += b5; a6 += b6; a7 += b7;
    a0 += __shfl_down(a0, 16); a1 += __shfl_down(a1, 16);
    a2 += __shfl_down(a2, 16); a3 += __shfl_down(a3, 16);
    a4 += __shfl_down(a4, 16); a5 += __shfl_down(a5, 16);
    a6 += __shfl_down(a6, 16); a7 += __shfl_down(a7, 16);
    a0 += __shfl_down(a0, 32); a1 += __shfl_down(a1, 32);
    a2 += __shfl_down(a2, 32); a3 += __shfl_down(a3, 32);
    a4 += __shfl_down(a4, 32); a5 += __shfl_down(a5, 32);
    a6 += __shfl_down(a6, 32); a7 += __shfl_down(a7, 32);
    if (quarter == 0) {
        int d = end - beg;
        float inv = 1.0f / (float)(d > 0 ? d : 1);
        ushort8 o;
        o[0] = (unsigned short)(__float_as_uint(a0 * inv) >> 16);
        o[1] = (unsigned short)(__float_as_uint(a1 * inv) >> 16);
        o[2] = (unsigned short)(__float_as_uint(a2 * inv) >> 16);
        o[3] = (unsigned short)(__float_as_uint(a3 * inv) >> 16);
        o[4] = (unsigned short)(__float_as_uint(a4 * inv) >> 16);
        o[5] = (unsigned short)(__float_as_uint(a5 * inv) >> 16);
        o[6] = (unsigned short)(__float_as_uint(a6 * inv) >> 16);
        o[7] = (unsigned short)(__float_as_uint(a7 * inv) >> 16);
        ((ushort8*)(mH + (size_t)n * 128))[li] = o;
    }
}

// ------------------- split-bf16 MFMA GEMM (layers 0,1) ---------------------

__global__ __launch_bounds__(256, 2) void sage_gemm_mfma(
    const unsigned short* __restrict__ a0H, const unsigned short* __restrict__ a1H,
    const unsigned short* __restrict__ wlH, const unsigned short* __restrict__ wlL,
    const unsigned short* __restrict__ wrH, const unsigned short* __restrict__ wrL,
    const float* __restrict__ bias,
    unsigned short* __restrict__ outH, int N) {
    __shared__ unsigned short Ah[128][40];
    __shared__ unsigned short Wh[128][40];
    __shared__ unsigned short Wl[128][40];
    int tid = threadIdx.x;
    int n0 = blockIdx.x * 128;
    int wv = tid >> 6, lane = tid & 63;
    int wm = wv & 1, wn = wv >> 1;
    int r16 = lane & 15, q = lane >> 4, q8 = q * 8;

    floatx4 acc[4][4];
#pragma unroll
    for (int mi = 0; mi < 4; ++mi)
#pragma unroll
        for (int ni = 0; ni < 4; ++ni) {
            floatx4 z = {0.f, 0.f, 0.f, 0.f};
            acc[mi][ni] = z;
        }

    int tc = (tid & 3) * 8;
    int tr = tid >> 2;

    for (int part = 0; part < 2; ++part) {
        const unsigned short* AH = part ? a1H : a0H;
        const unsigned short* WHp = part ? wrH : wlH;
        const unsigned short* WLp = part ? wrL : wlL;
        for (int kk = 0; kk < 128; kk += 32) {
            __syncthreads();
#pragma unroll
            for (int rr = 0; rr < 2; ++rr) {
                int row = tr + 64 * rr;
                int n = n0 + row;
                ushort8 vh = {0, 0, 0, 0, 0, 0, 0, 0};
                if (n < N) vh = *(const ushort8*)&AH[(size_t)n * 128 + kk + tc];
                *(ushort8*)&Ah[row][tc] = vh;
                *(ushort8*)&Wh[row][tc] = *(const ushort8*)&WHp[(size_t)row * 128 + kk + tc];
                *(ushort8*)&Wl[row][tc] = *(const ushort8*)&WLp[(size_t)row * 128 + kk + tc];
            }
            __syncthreads();
            short8 ah[4];
#pragma unroll
            for (int mi = 0; mi < 4; ++mi)
                ah[mi] = *(const short8*)&Ah[64 * wm + 16 * mi + r16][q8];
#pragma unroll
            for (int ni = 0; ni < 4; ++ni) {
                int row = 64 * wn + 16 * ni + r16;
                short8 bh = *(const short8*)&Wh[row][q8];
                short8 bl = *(const short8*)&Wl[row][q8];
#pragma unroll
                for (int mi = 0; mi < 4; ++mi) {
                    acc[mi][ni] = __builtin_amdgcn_mfma_f32_16x16x32_bf16(ah[mi], bh, acc[mi][ni], 0, 0, 0);
                    acc[mi][ni] = __builtin_amdgcn_mfma_f32_16x16x32_bf16(ah[mi], bl, acc[mi][ni], 0, 0, 0);
                }
            }
        }
    }

#pragma unroll
    for (int ni = 0; ni < 4; ++ni) {
        int j = 64 * wn + 16 * ni + r16;
        float b = bias[j];
#pragma unroll
        for (int mi = 0; mi < 4; ++mi) {
            floatx4 v = acc[mi][ni];
#pragma unroll
            for (int p = 0; p < 4; ++p) {
                int node = n0 + 64 * wm + 16 * mi + 4 * q + p;
                if (node < N) {
                    float val = fmaxf(v[p] + b, 0.f);
                    outH[(size_t)node * 128 + j] =
                        (unsigned short)(__float_as_uint(val) >> 16);
                }
            }
        }
    }
}

// ---------- layer-2 GEMM + head MLP fused (writes final out) ---------------
// Flat LDS overlays: staging (3x128x40=15360) vs head {Hs 128x136=17408,
// H1 128x68=8704} -> 26112 ushorts (52.2KB).
#define SM_AH 0
#define SM_WH 5120
#define SM_WL 10240
#define SM_HS 0          // h tile, stride 136 (reuses whole buffer after GEMM)
#define SM_H1 17408      // h1 tile, stride 68

__global__ __launch_bounds__(256, 2) void sage_gemm_head_fused(
    const unsigned short* __restrict__ a0H, const unsigned short* __restrict__ a1H,
    const unsigned short* __restrict__ wlH, const unsigned short* __restrict__ wlL,
    const unsigned short* __restrict__ wrH, const unsigned short* __restrict__ wrL,
    const float* __restrict__ bias,
    const unsigned short* __restrict__ wh1H, const unsigned short* __restrict__ wh1L,
    const float* __restrict__ bh1, const float* __restrict__ Wh2,
    const float* __restrict__ bh2, float* __restrict__ out, int N) {
    __shared__ unsigned short smem[26112];
    int tid = threadIdx.x;
    int n0 = blockIdx.x * 128;
    int wv = tid >> 6, lane = tid & 63;
    int wm = wv & 1, wn = wv >> 1;
    int r16 = lane & 15, q = lane >> 4, q8 = q * 8;

    floatx4 acc[4][4];
#pragma unroll
    for (int mi = 0; mi < 4; ++mi)
#pragma unroll
        for (int ni = 0; ni < 4; ++ni) {
            floatx4 z = {0.f, 0.f, 0.f, 0.f};
            acc[mi][ni] = z;
        }

    int tc = (tid & 3) * 8;
    int tr = tid >> 2;

    for (int part = 0; part < 2; ++part) {
        const unsigned short* AH = part ? a1H : a0H;
        const unsigned short* WHp = part ? wrH : wlH;
        const unsigned short* WLp = part ? wrL : wlL;
        for (int kk = 0; kk < 128; kk += 32) {
            __syncthreads();
#pragma unroll
            for (int rr = 0; rr < 2; ++rr) {
                int row = tr + 64 * rr;
                int n = n0 + row;
                ushort8 vh = {0, 0, 0, 0, 0, 0, 0, 0};
                if (n < N) vh = *(const ushort8*)&AH[(size_t)n * 128 + kk + tc];
                *(ushort8*)&smem[SM_AH + row * 40 + tc] = vh;
                *(ushort8*)&smem[SM_WH + row * 40 + tc] = *(const ushort8*)&WHp[(size_t)row * 128 + kk + tc];
                *(ushort8*)&smem[SM_WL + row * 40 + tc] = *(const ushort8*)&WLp[(size_t)row * 128 + kk + tc];
            }
            __syncthreads();
            short8 ah[4];
#pragma unroll
            for (int mi = 0; mi < 4; ++mi)
                ah[mi] = *(const short8*)&smem[SM_AH + (64 * wm + 16 * mi + r16) * 40 + q8];
#pragma unroll
            for (int ni = 0; ni < 4; ++ni) {
                int row = 64 * wn + 16 * ni + r16;
                short8 bh = *(const short8*)&smem[SM_WH + row * 40 + q8];
                short8 bl = *(const short8*)&smem[SM_WL + row * 40 + q8];
#pragma unroll
                for (int mi = 0; mi < 4; ++mi) {
                    acc[mi][ni] = __builtin_amdgcn_mfma_f32_16x16x32_bf16(ah[mi], bh, acc[mi][ni], 0, 0, 0);
                    acc[mi][ni] = __builtin_amdgcn_mfma_f32_16x16x32_bf16(ah[mi], bl, acc[mi][ni], 0, 0, 0);
                }
            }
        }
    }

    // epilogue: h = ReLU(acc + bias) -> Hs (bf16, row-major [node][feat])
    __syncthreads();   // staging arrays dead; reuse buffer as Hs
#pragma unroll
    for (int ni = 0; ni < 4; ++ni) {
        int j = 64 * wn + 16 * ni + r16;
        float b = bias[j];
#pragma unroll
        for (int mi = 0; mi < 4; ++mi) {
            floatx4 v = acc[mi][ni];
#pragma unroll
            for (int p = 0; p < 4; ++p) {
                int row = 64 * wm + 16 * mi + 4 * q + p;
                float val = fmaxf(v[p] + b, 0.f);
                smem[SM_HS + row * 136 + j] = (unsigned short)(__float_as_uint(val) >> 16);
            }
        }
    }
    __syncthreads();

    // head-1 MFMA: h1 = ReLU(h @ Wh1^T + bh1). M=128 (2 m-tiles/wave), N=64.
    floatx4 acc2[2][4];
#pragma unroll
    for (int t = 0; t < 2; ++t)
#pragma unroll
        for (int nt = 0; nt < 4; ++nt) {
            floatx4 z = {0.f, 0.f, 0.f, 0.f};
            acc2[t][nt] = z;
        }
#pragma unroll
    for (int ks = 0; ks < 4; ++ks) {
        short8 at[2];
#pragma unroll
        for (int t = 0; t < 2; ++t)
            at[t] = *(const short8*)&smem[SM_HS + (16 * (2 * wv + t) + r16) * 136 + 32 * ks + q8];
#pragma unroll
        for (int nt = 0; nt < 4; ++nt) {
            int jrow = 16 * nt + r16;
            short8 bh = *(const short8*)&wh1H[jrow * 128 + 32 * ks + q8];
            short8 bl = *(const short8*)&wh1L[jrow * 128 + 32 * ks + q8];
#pragma unroll
            for (int t = 0; t < 2; ++t) {
                acc2[t][nt] = __builtin_amdgcn_mfma_f32_16x16x32_bf16(at[t], bh, acc2[t][nt], 0, 0, 0);
                acc2[t][nt] = __builtin_amdgcn_mfma_f32_16x16x32_bf16(at[t], bl, acc2[t][nt], 0, 0, 0);
            }
        }
    }
    // h1 -> H1 (bf16)
#pragma unroll
    for (int nt = 0; nt < 4; ++nt) {
        int c = 16 * nt + r16;
        float b1 = bh1[c];
#pragma unroll
        for (int t = 0; t < 2; ++t) {
            floatx4 v = acc2[t][nt];
#pragma unroll
            for (int p = 0; p < 4; ++p) {
                int row = 16 * (2 * wv + t) + 4 * q + p;
                float val = fmaxf(v[p] + b1, 0.f);
                smem[SM_H1 + row * 68 + c] = (unsigned short)(__float_as_uint(val) >> 16);
            }
        }
    }
    __syncthreads();

    // head-2: out[n][c] = dot64(h1[n], Wh2[c]) + bh2[c]; thread -> (row, 2 c's)
    {
        int row = tid >> 1;
        int c0 = (tid & 1) * 2;
        int n = n0 + row;
        if (n < N) {
            const float* w0p = Wh2 + (size_t)c0 * 64;
            const float* w1p = w0p + 64;
            float s0 = bh2[c0], s1 = bh2[c0 + 1];
#pragma unroll 16
            for (int k = 0; k < 64; ++k) {
                float hv = bf2f(smem[SM_H1 + row * 68 + k]);
                s0 += hv * w0p[k];
                s1 += hv * w1p[k];
            }
            out[(size_t)n * 4 + c0] = s0;
            out[(size_t)n * 4 + c0 + 1] = s1;
        }
    }
}

// ------------------------------- launcher ----------------------------------

extern "C" void kernel_launch(void* const* d_in, const int* in_sizes, int n_in,
                              void* d_out, int out_size, void* d_ws, size_t ws_size,
                              hipStream_t stream) {
    const float* x   = (const float*)d_in[0];
    const int*   ei  = (const int*)d_in[1];
    const float* Wl0 = (const float*)d_in[2];
    const float* bl0 = (const float*)d_in[3];
    const float* Wr0 = (const float*)d_in[4];
    const float* Wl1 = (const float*)d_in[5];
    const float* bl1 = (const float*)d_in[6];
    const float* Wr1 = (const float*)d_in[7];
    const float* Wl2 = (const float*)d_in[8];
    const float* bl2 = (const float*)d_in[9];
    const float* Wr2 = (const float*)d_in[10];
    const float* Wh1 = (const float*)d_in[11];
    const float* bh1 = (const float*)d_in[12];
    const float* Wh2 = (const float*)d_in[13];
    const float* bh2 = (const float*)d_in[14];
    float* out = (float*)d_out;

    const int N = in_sizes[0] / 128;
    const int E = in_sizes[1] / 2;
    const int* src = ei;
    const int* dst = ei + E;
    const int NBUCK = ((N + 127) >> BSHIFT);

    int* row_ptr       = (int*)d_ws;                 // N+1
    int* bh            = row_ptr + N + 1;            // NBUCK
    int* bucket_base   = bh + NBUCK;                 // NBUCK+1
    int* bucket_cursor = bucket_base + NBUCK + 1;    // NBUCK
    unsigned int* ebuf = (unsigned int*)(bucket_cursor + NBUCK);  // E
    int* col           = (int*)(ebuf + E);           // E
    size_t ioff = (((size_t)(N + 1 + 3 * NBUCK + 1 + 2 * (size_t)E)) * sizeof(int) + 255) & ~(size_t)255;
    unsigned short* u0H = (unsigned short*)((char*)d_ws + ioff);  // x / hB hi
    unsigned short* mHb = u0H + (size_t)N * 128;                  // mean hi
    unsigned short* aH  = mHb + (size_t)N * 128;                  // hA hi
    unsigned short* WH  = aH + (size_t)N * 128;                   // 6x16384 + 8192 (Wh1)
    unsigned short* WL  = WH + 6 * 16384 + 8192;

    const int nb4 = (N + 3) / 4;
    const int gb128 = (N + 127) / 128;
    const int CHUNK = 2048;
    const int nchunk = (E + CHUNK - 1) / CHUNK;
    const int XB = (N * 32 + 255) / 256;
    const int WB = 104;                 // 96 (6 square mats) + 8 (Wh1)
    const int HB = 256;

    // CSR build + conversions
    hipMemsetAsync(bh, 0, (size_t)NBUCK * sizeof(int), stream);
    prep_kernel<<<XB + WB + HB, 256, 0, stream>>>(x, u0H, N * 32,
                                                  Wl0, Wr0, Wl1, Wr1, Wl2, Wr2, Wh1,
                                                  WH, WL, dst, E, bh, NBUCK, XB, WB, HB);
    bucket_scan_kernel<<<1, 512, 0, stream>>>(bh, bucket_base, bucket_cursor, row_ptr, NBUCK, N, E);
    binsort_kernel<<<nchunk, 256, 0, stream>>>(src, dst, E, CHUNK, bucket_cursor, ebuf, NBUCK);
    bucket_fill_kernel<<<NBUCK, 256, 0, stream>>>(bucket_base, ebuf, row_ptr, col, N);

    // layer 0
    agg_mean_kernel<<<nb4, 256, 0, stream>>>(u0H, row_ptr, col, mHb, N);
    sage_gemm_mfma<<<gb128, 256, 0, stream>>>(mHb, u0H,
                                              WH + 0 * 16384, WL + 0 * 16384,
                                              WH + 1 * 16384, WL + 1 * 16384,
                                              bl0, aH, N);
    // layer 1
    agg_mean_kernel<<<nb4, 256, 0, stream>>>(aH, row_ptr, col, mHb, N);
    sage_gemm_mfma<<<gb128, 256, 0, stream>>>(mHb, aH,
                                              WH + 2 * 16384, WL + 2 * 16384,
                                              WH + 3 * 16384, WL + 3 * 16384,
                                              bl1, u0H, N);
    // layer 2 + head (writes final out)
    agg_mean_kernel<<<nb4, 256, 0, stream>>>(u0H, row_ptr, col, mHb, N);
    sage_gemm_head_fused<<<gb128, 256, 0, stream>>>(mHb, u0H,
                                                    WH + 4 * 16384, WL + 4 * 16384,
                                                    WH + 5 * 16384, WL + 5 * 16384,
                                                    bl2,
                                                    WH + 6 * 16384, WL + 6 * 16384,
                                                    bh1, Wh2, bh2, out, N);
}